// Round 8
// baseline (5144.090 us; speedup 1.0000x reference)
//
#include <hip/hip_runtime.h>
#include <hip/hip_bf16.h>
#include <hip/hip_cooperative_groups.h>
#include <cstdint>
#include <cstddef>

namespace cg = cooperative_groups;

// Problem constants
#define KBLK 6
#define SL 257
#define BA 64
#define DM 1024
#define NHEAD 16
#define DRED 256
#define HDM 16
#define MR (SL * BA)     // 16448 real rows
#define MP 16512         // 129 * 128 padded rows
#define LNEPS 1e-5f

typedef __hip_bfloat16 bf16;
typedef __attribute__((ext_vector_type(8))) short short8;
typedef __attribute__((ext_vector_type(4))) short short4_t;
typedef __attribute__((ext_vector_type(4))) float f32x4;

__device__ __forceinline__ void gld_lds16(const void* g, void* l) {
  __builtin_amdgcn_global_load_lds(
      (const __attribute__((address_space(1))) unsigned int*)g,
      (__attribute__((address_space(3))) unsigned int*)l, 16, 0, 0);
}

__device__ __forceinline__ float bf2f(short s) {
  bf16 t = *reinterpret_cast<bf16*>(&s);
  return __bfloat162float(t);
}
__device__ __forceinline__ short f2bf(float f) {
  bf16 t = __float2bfloat16(f);
  return *reinterpret_cast<short*>(&t);
}

// ---------------- fused weight casts (one ordinary launch) ----------------
__global__ __launch_bounds__(256) void cast_all_kernel(
    const float* __restrict__ ipw, const float* __restrict__ opw,
    const float* __restrict__ fcw, const float* __restrict__ cpw,
    const float* __restrict__ proj,
    bf16* __restrict__ wq, bf16* __restrict__ wo, bf16* __restrict__ wfc,
    bf16* __restrict__ wcp, bf16* __restrict__ wpj) {
  const int blk = blockIdx.x;
  const int tid = threadIdx.x;
  const float* src;
  bf16* dst;
  int base;
  bool tr = false;
  if (blk < 2304)      { src = ipw; dst = wq;  base = blk * 2048; }
  else if (blk < 3072) { src = opw; dst = wo;  base = (blk - 2304) * 2048; }
  else if (blk < 6144) { src = fcw; dst = wfc; base = (blk - 3072) * 2048; }
  else if (blk < 9216) { src = cpw; dst = wcp; base = (blk - 6144) * 2048; }
  else                 { src = proj; dst = wpj; base = (blk - 9216) * 2048; tr = true; }
  const int idx = base + tid * 8;
  short8 o;
  if (!tr) {
    float4 a = *(const float4*)(src + idx);
    float4 b = *(const float4*)(src + idx + 4);
    o[0] = f2bf(a.x); o[1] = f2bf(a.y); o[2] = f2bf(a.z); o[3] = f2bf(a.w);
    o[4] = f2bf(b.x); o[5] = f2bf(b.y); o[6] = f2bf(b.z); o[7] = f2bf(b.w);
  } else {
    int n = idx >> 10, k = idx & 1023;
#pragma unroll
    for (int e = 0; e < 8; ++e) o[e] = f2bf(src[(size_t)(k + e) * 768 + n]);
  }
  *(short8*)(dst + idx) = o;
}

// ---------------- shared-memory union for the mega kernel ----------------
union __align__(16) MegaLds {
  char gemm[32768];
  struct {
    short kl[272][24];   // 13056 B
    short vt[16][296];   //  9472 B
    short pl[4][16][40]; //  5120 B
  } at;                  // 27648 B total
  float red[8];
};

// ---------------- LN phase (strided rows) ----------------
// mode 0: x=bf16(hook); LN(hook)->hout | mode 2: LN(x)->hout | mode 3: LN(x)->hout transposed
__device__ __forceinline__ void ph_ln(int mode, int nwg, int wg,
    const float* __restrict__ hk, bf16* __restrict__ x, bf16* __restrict__ hout,
    const float* __restrict__ w, const float* __restrict__ bb, float* red) {
  const int tid = threadIdx.x;
  for (int row = wg; row < MR; row += nwg) {
    const size_t base = (size_t)row * DM + tid * 4;
    float vals[4];
    if (mode == 0) {
      float4 v = *(const float4*)(hk + base);
      vals[0] = v.x; vals[1] = v.y; vals[2] = v.z; vals[3] = v.w;
      short4_t pk;
#pragma unroll
      for (int j = 0; j < 4; ++j) pk[j] = f2bf(vals[j]);
      *(short4_t*)&x[base] = pk;
    } else {
      short4_t xv = *(const short4_t*)&x[base];
#pragma unroll
      for (int j = 0; j < 4; ++j) vals[j] = bf2f(xv[j]);
    }
    float s1 = vals[0] + vals[1] + vals[2] + vals[3];
    float s2 = vals[0] * vals[0] + vals[1] * vals[1] + vals[2] * vals[2] + vals[3] * vals[3];
#pragma unroll
    for (int o = 32; o >= 1; o >>= 1) {
      s1 += __shfl_down(s1, o);
      s2 += __shfl_down(s2, o);
    }
    if ((tid & 63) == 0) {
      red[tid >> 6] = s1;
      red[4 + (tid >> 6)] = s2;
    }
    __syncthreads();
    s1 = red[0] + red[1] + red[2] + red[3];
    s2 = red[4] + red[5] + red[6] + red[7];
    const float mu = s1 * (1.f / DM);
    const float rs = rsqrtf(s2 * (1.f / DM) - mu * mu + LNEPS);
    size_t orow = row;
    if (mode == 3) {
      int s = row >> 6, b2 = row & 63;
      orow = (size_t)b2 * SL + s;
    }
    const int c = tid * 4;
    short4_t pk;
#pragma unroll
    for (int j = 0; j < 4; ++j)
      pk[j] = f2bf((vals[j] - mu) * rs * w[c + j] + bb[c + j]);
    *(short4_t*)((char*)hout + (orow * DM + c) * 2) = pk;
    __syncthreads();  // protect red before next row
  }
}

// ---------------- attention phase (strided bh; validated algorithm, ql dropped) ----------------
__device__ __forceinline__ void ph_attn(int nwg, int wg, MegaLds* L,
                                        const bf16* __restrict__ qkv,
                                        bf16* __restrict__ obuf) {
  const int tid = threadIdx.x;
  const int wave = tid >> 6, lane = tid & 63;
  const int g = lane >> 4, qi = lane & 15;
  const short8 zero8 = {0, 0, 0, 0, 0, 0, 0, 0};
  const f32x4 fzero = {0.f, 0.f, 0.f, 0.f};

  for (int bh = wg; bh < BA * NHEAD; bh += nwg) {
    const int b = bh >> 4, h = bh & 15;
    // stage K (lds) and V^T (lds): 2 arrays * 272 rows * 2 halves
    for (int task = tid; task < 1088; task += 256) {
      int a = (task < 544) ? 1 : 2;
      int rem = (task < 544) ? task : task - 544;
      int row = rem >> 1, half = rem & 1;
      short8 v = zero8;
      if (row < SL)
        v = *(const short8*)((const short*)qkv + (size_t)(row * BA + b) * 768 + a * 256 + h * 16 + half * 8);
      if (a == 1) *(short8*)&L->at.kl[row][half * 8] = v;
      else {
#pragma unroll
        for (int j = 0; j < 8; ++j) L->at.vt[half * 8 + j][row] = v[j];
      }
    }
    for (int i = tid; i < 16 * 24; i += 256) L->at.vt[i / 24][272 + (i % 24)] = 0;
    __syncthreads();

    for (int t = wave; t < 17; t += 4) {
      const int qrow = t * 16 + qi;
      short8 bq = zero8;
      if (g < 2 && qrow < SL)
        bq = *(const short8*)((const short*)qkv + (size_t)(qrow * BA + b) * 768 + h * 16 + g * 8);

      f32x4 st[18];
#pragma unroll
      for (int t2 = 0; t2 < 17; ++t2) {
        short8 ak = zero8;
        if (g < 2) ak = *(const short8*)&L->at.kl[t2 * 16 + qi][g * 8];
        st[t2] = __builtin_amdgcn_mfma_f32_16x16x32_bf16(ak, bq, fzero, 0, 0, 0);
      }
      float mx = -1e30f;
#pragma unroll
      for (int t2 = 0; t2 < 17; ++t2) {
#pragma unroll
        for (int r = 0; r < 4; ++r) {
          int s = t2 * 16 + g * 4 + r;
          float v = (s <= 256) ? st[t2][r] * 0.25f : -1e30f;
          st[t2][r] = v;
          mx = fmaxf(mx, v);
        }
      }
      mx = fmaxf(mx, __shfl_xor(mx, 16));
      mx = fmaxf(mx, __shfl_xor(mx, 32));
      float ls = 0.f;
#pragma unroll
      for (int t2 = 0; t2 < 17; ++t2) {
#pragma unroll
        for (int r = 0; r < 4; ++r) {
          float p = __expf(st[t2][r] - mx);
          st[t2][r] = p;
          ls += p;
        }
      }
      ls += __shfl_xor(ls, 16);
      ls += __shfl_xor(ls, 32);
      const float inv = 1.f / ls;
#pragma unroll
      for (int t2 = 0; t2 < 17; ++t2)
#pragma unroll
        for (int r = 0; r < 4; ++r) st[t2][r] *= inv;
      st[17] = fzero;

      f32x4 acc = fzero;
#pragma unroll
      for (int tt = 0; tt < 9; ++tt) {
#pragma unroll
        for (int hh = 0; hh < 2; ++hh) {
          int t2 = tt * 2 + hh;
          short4_t pk;
#pragma unroll
          for (int r = 0; r < 4; ++r) pk[r] = f2bf(st[t2][r]);
          *(short4_t*)&L->at.pl[wave][qi][hh * 16 + g * 4] = pk;
        }
        short8 pa = *(const short8*)&L->at.pl[wave][qi][g * 8];
        short8 bv = *(const short8*)&L->at.vt[qi][tt * 32 + g * 8];
        acc = __builtin_amdgcn_mfma_f32_16x16x32_bf16(pa, bv, acc, 0, 0, 0);
      }
#pragma unroll
      for (int r = 0; r < 4; ++r) {
        int qr = t * 16 + g * 4 + r;
        if (qr < SL)
          obuf[(size_t)(qr * BA + b) * DRED + h * 16 + qi] = __float2bfloat16(acc[r]);
      }
    }
    __syncthreads();  // protect LDS before next bh staging
  }
}

// ---------------- GEMM phase (strided tiles; round-7 validated body) ----------------
// C(M,N) = A(M,K)*Bw(N,K)^T + bias, 128x128 tile, swapped mfma operands.
// EPI 0 fp32 write | 1 bf16 RMW += | 2 bf16 quickgelu | 3 bf16 write | 4 gated residual RMW
template <int EPI>
__device__ __forceinline__ void ph_gemm(int nwg, int wg, char* lds,
    const bf16* __restrict__ A, int lda,
    const bf16* __restrict__ Bw, int ldb,
    const float* __restrict__ bias,
    void* __restrict__ C, int ldc,
    int Kdim, int nT, int ntiles,
    const float* __restrict__ hook, const float* __restrict__ alphap, int kidx) {
  const int tid = threadIdx.x;
  const int wave = tid >> 6, lane = tid & 63;
  const int lrow = lane & 15, lk = lane >> 4;
  const int wr = wave >> 1, wc = wave & 1;
  const int q = ntiles >> 3, r = ntiles & 7;
  const int nk = Kdim >> 6;

  float wmg = 0.f, omg = 0.f;
  if (EPI == 4) {
    wmg = 1.f / (1.f + __expf(-alphap[kidx] * 10.f));
    omg = 1.f - wmg;
  }

  for (int t0 = wg; t0 < ntiles; t0 += nwg) {
    const int xcd = t0 & 7, idx = t0 >> 3;
    const int wgid = (xcd < r ? xcd * (q + 1) : r * (q + 1) + (xcd - r) * q) + idx;
    const int m0 = (wgid / nT) * 128;
    const int n0 = (wgid % nT) * 128;

    f32x4 acc[4][4];
    const f32x4 zero = {0.f, 0.f, 0.f, 0.f};
#pragma unroll
    for (int i = 0; i < 4; ++i)
#pragma unroll
      for (int j = 0; j < 4; ++j) acc[i][j] = zero;

    for (int kt = 0; kt < nk; ++kt) {
      const int k0 = kt << 6;
#pragma unroll
      for (int j = 0; j < 4; ++j) {
        int c = wave * 256 + j * 64 + lane;
        int row = c >> 3, segp = c & 7;
        int seg = segp ^ (row & 7);
        gld_lds16(A + (size_t)(m0 + row) * lda + k0 + seg * 8, &lds[c * 16]);
        gld_lds16(Bw + (size_t)(n0 + row) * ldb + k0 + seg * 8, &lds[16384 + c * 16]);
      }
      __syncthreads();
#pragma unroll
      for (int kh = 0; kh < 2; ++kh) {
        short8 af[4], bfr[4];
#pragma unroll
        for (int i = 0; i < 4; ++i) {
          int rr = wr * 64 + i * 16 + lrow;
          int seg = kh * 4 + lk;
          af[i] = *(const short8*)(lds + rr * 128 + ((seg ^ (rr & 7)) << 4));
        }
#pragma unroll
        for (int j = 0; j < 4; ++j) {
          int rr = wc * 64 + j * 16 + lrow;
          int seg = kh * 4 + lk;
          bfr[j] = *(const short8*)(lds + 16384 + rr * 128 + ((seg ^ (rr & 7)) << 4));
        }
#pragma unroll
        for (int i = 0; i < 4; ++i)
#pragma unroll
          for (int j = 0; j < 4; ++j)
            acc[i][j] = __builtin_amdgcn_mfma_f32_16x16x32_bf16(bfr[j], af[i], acc[i][j], 0, 0, 0);
      }
      __syncthreads();
    }

#pragma unroll
    for (int i = 0; i < 4; ++i) {
      const int row = m0 + wr * 64 + i * 16 + lrow;
      if (row >= MR) continue;
#pragma unroll
      for (int j = 0; j < 4; ++j) {
        const int col = n0 + wc * 64 + j * 16 + lk * 4;
        const size_t off = (size_t)row * ldc + col;
        float bv[4] = {0.f, 0.f, 0.f, 0.f};
        if (bias) {
          float4 b4 = *(const float4*)&bias[col];
          bv[0] = b4.x; bv[1] = b4.y; bv[2] = b4.z; bv[3] = b4.w;
        }
        float v[4];
#pragma unroll
        for (int rr = 0; rr < 4; ++rr) v[rr] = acc[i][j][rr] + bv[rr];
        if (EPI == 0) {
          float4 o4 = {v[0], v[1], v[2], v[3]};
          *(float4*)((float*)C + off) = o4;
        } else if (EPI == 2) {
          short4_t pk;
#pragma unroll
          for (int rr = 0; rr < 4; ++rr)
            pk[rr] = f2bf(v[rr] / (1.f + __expf(-1.702f * v[rr])));
          *(short4_t*)((bf16*)C + off) = pk;
        } else if (EPI == 3) {
          short4_t pk;
#pragma unroll
          for (int rr = 0; rr < 4; ++rr) pk[rr] = f2bf(v[rr]);
          *(short4_t*)((bf16*)C + off) = pk;
        } else if (EPI == 1) {
          short4_t xv = *(const short4_t*)((const bf16*)C + off);
          short4_t pk;
#pragma unroll
          for (int rr = 0; rr < 4; ++rr) pk[rr] = f2bf(bf2f(xv[rr]) + v[rr]);
          *(short4_t*)((bf16*)C + off) = pk;
        } else {  // EPI 4
          short4_t xv = *(const short4_t*)((const bf16*)C + off);
          float4 h4 = *(const float4*)&hook[off];
          float hk[4] = {h4.x, h4.y, h4.z, h4.w};
          short4_t pk;
#pragma unroll
          for (int rr = 0; rr < 4; ++rr)
            pk[rr] = f2bf(wmg * hk[rr] + omg * (bf2f(xv[rr]) + v[rr]));
          *(short4_t*)((bf16*)C + off) = pk;
        }
      }
    }
  }
}

// ---------------- mega kernel: whole network, one cooperative launch ----------------
__global__ __launch_bounds__(256, 4) void mega_kernel(
    const float* hook, const float* alpha,
    const float* ipb, const float* opb,
    const float* l1w, const float* l1b, const float* l2w, const float* l2b,
    const float* fcb, const float* cpb, const float* lpw, const float* lpb,
    bf16* x, bf16* hbuf, bf16* qkv, bf16* obuf,
    const bf16* wq, const bf16* wo, const bf16* wfc, const bf16* wcp, const bf16* wpj,
    float* outp) {
  cg::grid_group grid = cg::this_grid();
  __shared__ MegaLds L;
  const int wg = blockIdx.x, nwg = gridDim.x;
  bf16* mbuf = qkv;  // reuse (phases separated by grid syncs)

  for (int i = 0; i < KBLK; ++i) {
    ph_ln(i == 0 ? 0 : 2, nwg, wg, hook, x, hbuf, l1w + i * DM, l1b + i * DM, L.red);
    grid.sync();
    ph_gemm<3>(nwg, wg, L.gemm, hbuf, DM, wq + (size_t)i * 768 * DM, DM,
               ipb + i * 768, qkv, 768, DM, 6, 774, nullptr, nullptr, 0);
    grid.sync();
    ph_attn(nwg, wg, &L, qkv, obuf);
    grid.sync();
    ph_gemm<1>(nwg, wg, L.gemm, obuf, DRED, wo + (size_t)i * DM * DRED, DRED,
               opb + i * DM, x, DM, DRED, 8, 1032, nullptr, nullptr, 0);
    grid.sync();
    ph_ln(2, nwg, wg, nullptr, x, hbuf, l2w + i * DM, l2b + i * DM, L.red);
    grid.sync();
    ph_gemm<2>(nwg, wg, L.gemm, hbuf, DM, wfc + (size_t)i * DM * DM, DM,
               fcb + i * DM, mbuf, DM, DM, 8, 1032, nullptr, nullptr, 0);
    grid.sync();
    if (i + 1 < KBLK)
      ph_gemm<4>(nwg, wg, L.gemm, mbuf, DM, wcp + (size_t)i * DM * DM, DM,
                 cpb + i * DM, x, DM, DM, 8, 1032,
                 hook + (size_t)(i + 1) * MR * DM, alpha, i + 1);
    else
      ph_gemm<1>(nwg, wg, L.gemm, mbuf, DM, wcp + (size_t)i * DM * DM, DM,
                 cpb + i * DM, x, DM, DM, 8, 1032, nullptr, nullptr, 0);
    grid.sync();
  }
  ph_ln(3, nwg, wg, nullptr, x, hbuf, lpw, lpb, L.red);
  grid.sync();
  ph_gemm<0>(nwg, wg, L.gemm, hbuf, DM, wpj, DM, nullptr,
             outp, 768, DM, 6, 774, nullptr, nullptr, 0);
}

// ---------------- driver ----------------
extern "C" void kernel_launch(void* const* d_in, const int* in_sizes, int n_in,
                              void* d_out, int out_size, void* d_ws, size_t ws_size,
                              hipStream_t stream) {
  const float* hook = (const float*)d_in[0];
  const float* alpha = (const float*)d_in[1];
  const float* ipw = (const float*)d_in[2];
  const float* ipb = (const float*)d_in[3];
  const float* opw = (const float*)d_in[4];
  const float* opb = (const float*)d_in[5];
  const float* l1w = (const float*)d_in[6];
  const float* l1b = (const float*)d_in[7];
  const float* l2w = (const float*)d_in[8];
  const float* l2b = (const float*)d_in[9];
  const float* fcw = (const float*)d_in[10];
  const float* fcb = (const float*)d_in[11];
  const float* cpw = (const float*)d_in[12];
  const float* cpb = (const float*)d_in[13];
  const float* lpw = (const float*)d_in[14];
  const float* lpb = (const float*)d_in[15];
  const float* proj = (const float*)d_in[16];

  char* ws = (char*)d_ws;
  size_t off = 0;
  bf16* x = (bf16*)(ws + off); off += (size_t)MP * DM * 2;
  bf16* hbuf = (bf16*)(ws + off); off += (size_t)MP * DM * 2;
  bf16* qkv = (bf16*)(ws + off); off += (size_t)MP * 1024 * 2;
  bf16* obuf = (bf16*)(ws + off); off += (size_t)MP * DRED * 2;
  bf16* wq = (bf16*)(ws + off); off += (size_t)KBLK * 768 * DM * 2;
  bf16* wo = (bf16*)(ws + off); off += (size_t)KBLK * DM * DRED * 2;
  bf16* wfc = (bf16*)(ws + off); off += (size_t)KBLK * DM * DM * 2;
  bf16* wcp = (bf16*)(ws + off); off += (size_t)KBLK * DM * DM * 2;
  bf16* wpj = (bf16*)(ws + off); off += (size_t)768 * DM * 2;

  cast_all_kernel<<<9600, 256, 0, stream>>>(ipw, opw, fcw, cpw, proj,
                                            wq, wo, wfc, wcp, wpj);

  int occ = 0;
  hipOccupancyMaxActiveBlocksPerMultiprocessor(&occ, mega_kernel, 256, 0);
  int gw = occ * 256;         // 256 CUs on MI355X
  if (gw > 1024) gw = 1024;   // phase mappings sized for <= 1024
  if (gw < 256) gw = 256;
  float* outp = (float*)d_out;

  void* params[] = {
      (void*)&hook, (void*)&alpha, (void*)&ipb, (void*)&opb,
      (void*)&l1w, (void*)&l1b, (void*)&l2w, (void*)&l2b,
      (void*)&fcb, (void*)&cpb, (void*)&lpw, (void*)&lpb,
      (void*)&x, (void*)&hbuf, (void*)&qkv, (void*)&obuf,
      (void*)&wq, (void*)&wo, (void*)&wfc, (void*)&wcp, (void*)&wpj,
      (void*)&outp};
  hipLaunchCooperativeKernel((void*)mega_kernel, dim3(gw), dim3(256),
                             params, 0, stream);
}

// Round 9
// 4427.336 us; speedup vs baseline: 1.1619x; 1.1619x over previous
//
#include <hip/hip_runtime.h>
#include <hip/hip_bf16.h>
#include <cstdint>
#include <cstddef>

// Problem constants
#define KBLK 6
#define SL 257
#define BA 64
#define DM 1024
#define NHEAD 16
#define DRED 256
#define HDM 16
#define MR (SL * BA)     // 16448 real rows
#define MP 16512         // 129 * 128 padded rows
#define LNEPS 1e-5f
#define NPANEL 129
#define NCNT (12 * NPANEL)

typedef __hip_bfloat16 bf16;
typedef __attribute__((ext_vector_type(8))) short short8;
typedef __attribute__((ext_vector_type(4))) short short4_t;
typedef __attribute__((ext_vector_type(4))) float f32x4;

__device__ __forceinline__ void gld_lds16(const void* g, void* l) {
  __builtin_amdgcn_global_load_lds(
      (const __attribute__((address_space(1))) unsigned int*)g,
      (__attribute__((address_space(3))) unsigned int*)l, 16, 0, 0);
}

__device__ __forceinline__ float bf2f(short s) {
  bf16 t = *reinterpret_cast<bf16*>(&s);
  return __bfloat162float(t);
}
__device__ __forceinline__ short f2bf(float f) {
  bf16 t = __float2bfloat16(f);
  return *reinterpret_cast<short*>(&t);
}

// ---------------- fused weight casts + counter zeroing (one launch) ----------------
__global__ __launch_bounds__(256) void cast_all_kernel(
    const float* __restrict__ ipw, const float* __restrict__ opw,
    const float* __restrict__ fcw, const float* __restrict__ cpw,
    const float* __restrict__ proj,
    bf16* __restrict__ wq, bf16* __restrict__ wo, bf16* __restrict__ wfc,
    bf16* __restrict__ wcp, bf16* __restrict__ wpj, int* __restrict__ cnt) {
  const int blk = blockIdx.x;
  const int tid = threadIdx.x;
  if (blk == 0) {
    for (int z = tid; z < NCNT; z += 256) cnt[z] = 0;
  }
  const float* src;
  bf16* dst;
  int base;
  bool tr = false;
  if (blk < 2304)      { src = ipw; dst = wq;  base = blk * 2048; }
  else if (blk < 3072) { src = opw; dst = wo;  base = (blk - 2304) * 2048; }
  else if (blk < 6144) { src = fcw; dst = wfc; base = (blk - 3072) * 2048; }
  else if (blk < 9216) { src = cpw; dst = wcp; base = (blk - 6144) * 2048; }
  else                 { src = proj; dst = wpj; base = (blk - 9216) * 2048; tr = true; }
  const int idx = base + tid * 8;
  short8 o;
  if (!tr) {
    float4 a = *(const float4*)(src + idx);
    float4 b = *(const float4*)(src + idx + 4);
    o[0] = f2bf(a.x); o[1] = f2bf(a.y); o[2] = f2bf(a.z); o[3] = f2bf(a.w);
    o[4] = f2bf(b.x); o[5] = f2bf(b.y); o[6] = f2bf(b.z); o[7] = f2bf(b.w);
  } else {
    int n = idx >> 10, k = idx & 1023;
#pragma unroll
    for (int e = 0; e < 8; ++e) o[e] = f2bf(src[(size_t)(k + e) * 768 + n]);
  }
  *(short8*)(dst + idx) = o;
}

// ---------------- standalone LayerNorm (block 0 LN1 only) ----------------
__global__ __launch_bounds__(256) void ln0_kernel(
    const float* __restrict__ hook,
    bf16* __restrict__ x, bf16* __restrict__ hout,
    const float* __restrict__ w, const float* __restrict__ bb) {
  const int row = blockIdx.x;
  const int tid = threadIdx.x;
  const size_t base = (size_t)row * DM + tid * 4;
  float vals[4];
  float4 v = *(const float4*)(hook + base);
  vals[0] = v.x; vals[1] = v.y; vals[2] = v.z; vals[3] = v.w;
  short4_t pk0;
#pragma unroll
  for (int j = 0; j < 4; ++j) pk0[j] = f2bf(vals[j]);
  *(short4_t*)&x[base] = pk0;
  float s1 = vals[0] + vals[1] + vals[2] + vals[3];
  float s2 = vals[0] * vals[0] + vals[1] * vals[1] + vals[2] * vals[2] + vals[3] * vals[3];
#pragma unroll
  for (int o = 32; o >= 1; o >>= 1) {
    s1 += __shfl_down(s1, o);
    s2 += __shfl_down(s2, o);
  }
  __shared__ float red[8];
  if ((tid & 63) == 0) {
    red[tid >> 6] = s1;
    red[4 + (tid >> 6)] = s2;
  }
  __syncthreads();
  s1 = red[0] + red[1] + red[2] + red[3];
  s2 = red[4] + red[5] + red[6] + red[7];
  const float mu = s1 * (1.f / DM);
  const float rs = rsqrtf(s2 * (1.f / DM) - mu * mu + LNEPS);
  const int c = tid * 4;
  short4_t pk;
#pragma unroll
  for (int j = 0; j < 4; ++j)
    pk[j] = f2bf((vals[j] - mu) * rs * w[c + j] + bb[c + j]);
  *(short4_t*)((char*)hout + ((size_t)row * DM + c) * 2) = pk;
}

// ---------------- MFMA attention (validated) ----------------
__global__ __launch_bounds__(256) void attn_mfma_kernel(const bf16* __restrict__ qkv,
                                                        bf16* __restrict__ obuf) {
  __shared__ __align__(16) short ql[272][24];
  __shared__ __align__(16) short kl[272][24];
  __shared__ __align__(16) short vt[16][296];
  __shared__ __align__(16) short pl[4][16][40];
  const int bh = blockIdx.x;
  const int b = bh >> 4, h = bh & 15;
  const int tid = threadIdx.x;
  const int wave = tid >> 6, lane = tid & 63;
  const int g = lane >> 4, qi = lane & 15;

  const short8 zero8 = {0, 0, 0, 0, 0, 0, 0, 0};
  const f32x4 fzero = {0.f, 0.f, 0.f, 0.f};

  for (int task = tid; task < 1632; task += 256) {
    int a, rem;
    if (task < 544) { a = 0; rem = task; }
    else if (task < 1088) { a = 1; rem = task - 544; }
    else { a = 2; rem = task - 1088; }
    int row = rem >> 1, half = rem & 1;
    short8 v = zero8;
    if (row < SL)
      v = *(const short8*)((const short*)qkv + (size_t)(row * BA + b) * 768 + a * 256 + h * 16 + half * 8);
    if (a == 0) *(short8*)&ql[row][half * 8] = v;
    else if (a == 1) *(short8*)&kl[row][half * 8] = v;
    else {
#pragma unroll
      for (int j = 0; j < 8; ++j) vt[half * 8 + j][row] = v[j];
    }
  }
  for (int i = tid; i < 16 * 24; i += 256) vt[i / 24][272 + (i % 24)] = 0;
  __syncthreads();

  for (int t = wave; t < 17; t += 4) {
    short8 bq = zero8;
    if (g < 2) bq = *(const short8*)&ql[t * 16 + qi][g * 8];

    f32x4 st[18];
#pragma unroll
    for (int t2 = 0; t2 < 17; ++t2) {
      short8 ak = zero8;
      if (g < 2) ak = *(const short8*)&kl[t2 * 16 + qi][g * 8];
      st[t2] = __builtin_amdgcn_mfma_f32_16x16x32_bf16(ak, bq, fzero, 0, 0, 0);
    }
    float mx = -1e30f;
#pragma unroll
    for (int t2 = 0; t2 < 17; ++t2) {
#pragma unroll
      for (int r = 0; r < 4; ++r) {
        int s = t2 * 16 + g * 4 + r;
        float v = (s <= 256) ? st[t2][r] * 0.25f : -1e30f;
        st[t2][r] = v;
        mx = fmaxf(mx, v);
      }
    }
    mx = fmaxf(mx, __shfl_xor(mx, 16));
    mx = fmaxf(mx, __shfl_xor(mx, 32));
    float ls = 0.f;
#pragma unroll
    for (int t2 = 0; t2 < 17; ++t2) {
#pragma unroll
      for (int r = 0; r < 4; ++r) {
        float p = __expf(st[t2][r] - mx);
        st[t2][r] = p;
        ls += p;
      }
    }
    ls += __shfl_xor(ls, 16);
    ls += __shfl_xor(ls, 32);
    const float inv = 1.f / ls;
#pragma unroll
    for (int t2 = 0; t2 < 17; ++t2)
#pragma unroll
      for (int r = 0; r < 4; ++r) st[t2][r] *= inv;
    st[17] = fzero;

    f32x4 acc = fzero;
#pragma unroll
    for (int tt = 0; tt < 9; ++tt) {
#pragma unroll
      for (int hh = 0; hh < 2; ++hh) {
        int t2 = tt * 2 + hh;
        short4_t pk;
#pragma unroll
        for (int r = 0; r < 4; ++r) pk[r] = f2bf(st[t2][r]);
        *(short4_t*)&pl[wave][qi][hh * 16 + g * 4] = pk;
      }
      short8 pa = *(const short8*)&pl[wave][qi][g * 8];
      short8 bv = *(const short8*)&vt[qi][tt * 32 + g * 8];
      acc = __builtin_amdgcn_mfma_f32_16x16x32_bf16(pa, bv, acc, 0, 0, 0);
    }
#pragma unroll
    for (int r = 0; r < 4; ++r) {
      int qr = t * 16 + g * 4 + r;
      if (qr < SL)
        obuf[(size_t)(qr * BA + b) * DRED + h * 16 + qi] = __float2bfloat16(acc[r]);
    }
  }
}

// ---------------- unified 128x128 GEMM (round-7 validated) + optional fused LN ----------------
// EPI 0 fp32 write | 1 bf16 RMW += | 2 bf16 quickgelu | 3 bf16 write | 4 gated residual RMW
// FLN 0 none | 1 last-arrival LN of the 128-row panel -> lnout | 2 same but transposed (ln_post)
template <int EPI, int FLN>
__global__ __launch_bounds__(256, 4) void gemm_kernel(
    const bf16* __restrict__ A, int lda,
    const bf16* __restrict__ Bw, int ldb,
    const float* __restrict__ bias,
    void* __restrict__ C, int ldc,
    int Kdim, int Mreal,
    const float* __restrict__ hook, const float* __restrict__ alphap, int kidx,
    const float* __restrict__ lnw, const float* __restrict__ lnb,
    bf16* __restrict__ lnout, int* __restrict__ cnt) {
  __shared__ char lds[32768];
  const int tid = threadIdx.x;
  const int wave = tid >> 6, lane = tid & 63;
  const int lrow = lane & 15, lk = lane >> 4;
  const int wr = wave >> 1, wc = wave & 1;

  const int gx = gridDim.x, gy = gridDim.y;
  const int nwg = gx * gy;
  const int orig = blockIdx.y * gx + blockIdx.x;
  const int q = nwg >> 3, r = nwg & 7;
  const int xcd = orig & 7, idx = orig >> 3;
  const int wgid = (xcd < r ? xcd * (q + 1) : r * (q + 1) + (xcd - r) * q) + idx;
  const int m0 = (wgid / gy) * 128;
  const int n0 = (wgid % gy) * 128;

  f32x4 acc[4][4];
  const f32x4 zero = {0.f, 0.f, 0.f, 0.f};
#pragma unroll
  for (int i = 0; i < 4; ++i)
#pragma unroll
    for (int j = 0; j < 4; ++j) acc[i][j] = zero;

  const int nk = Kdim >> 6;

  for (int kt = 0; kt < nk; ++kt) {
    const int k0 = kt << 6;
#pragma unroll
    for (int j = 0; j < 4; ++j) {
      int c = wave * 256 + j * 64 + lane;
      int row = c >> 3, segp = c & 7;
      int seg = segp ^ (row & 7);
      gld_lds16(A + (size_t)(m0 + row) * lda + k0 + seg * 8, &lds[c * 16]);
      gld_lds16(Bw + (size_t)(n0 + row) * ldb + k0 + seg * 8, &lds[16384 + c * 16]);
    }
    __syncthreads();
#pragma unroll
    for (int kh = 0; kh < 2; ++kh) {
      short8 af[4], bfr[4];
#pragma unroll
      for (int i = 0; i < 4; ++i) {
        int rr = wr * 64 + i * 16 + lrow;
        int seg = kh * 4 + lk;
        af[i] = *(const short8*)(lds + rr * 128 + ((seg ^ (rr & 7)) << 4));
      }
#pragma unroll
      for (int j = 0; j < 4; ++j) {
        int rr = wc * 64 + j * 16 + lrow;
        int seg = kh * 4 + lk;
        bfr[j] = *(const short8*)(lds + 16384 + rr * 128 + ((seg ^ (rr & 7)) << 4));
      }
#pragma unroll
      for (int i = 0; i < 4; ++i)
#pragma unroll
        for (int j = 0; j < 4; ++j)
          acc[i][j] = __builtin_amdgcn_mfma_f32_16x16x32_bf16(bfr[j], af[i], acc[i][j], 0, 0, 0);
    }
    __syncthreads();
  }

  float wmg = 0.f, omg = 0.f;
  if (EPI == 4) {
    wmg = 1.f / (1.f + __expf(-alphap[kidx] * 10.f));
    omg = 1.f - wmg;
  }
#pragma unroll
  for (int i = 0; i < 4; ++i) {
    const int row = m0 + wr * 64 + i * 16 + lrow;
    if (row >= Mreal) continue;
#pragma unroll
    for (int j = 0; j < 4; ++j) {
      const int col = n0 + wc * 64 + j * 16 + lk * 4;
      const size_t off = (size_t)row * ldc + col;
      float bv[4] = {0.f, 0.f, 0.f, 0.f};
      if (bias) {
        float4 b4 = *(const float4*)&bias[col];
        bv[0] = b4.x; bv[1] = b4.y; bv[2] = b4.z; bv[3] = b4.w;
      }
      float v[4];
#pragma unroll
      for (int rr = 0; rr < 4; ++rr) v[rr] = acc[i][j][rr] + bv[rr];
      if (EPI == 0) {
        float4 o4 = {v[0], v[1], v[2], v[3]};
        *(float4*)((float*)C + off) = o4;
      } else if (EPI == 2) {
        short4_t pk;
#pragma unroll
        for (int rr = 0; rr < 4; ++rr)
          pk[rr] = f2bf(v[rr] / (1.f + __expf(-1.702f * v[rr])));
        *(short4_t*)((bf16*)C + off) = pk;
      } else if (EPI == 3) {
        short4_t pk;
#pragma unroll
        for (int rr = 0; rr < 4; ++rr) pk[rr] = f2bf(v[rr]);
        *(short4_t*)((bf16*)C + off) = pk;
      } else if (EPI == 1) {
        short4_t xv = *(const short4_t*)((const bf16*)C + off);
        short4_t pk;
#pragma unroll
        for (int rr = 0; rr < 4; ++rr) pk[rr] = f2bf(bf2f(xv[rr]) + v[rr]);
        *(short4_t*)((bf16*)C + off) = pk;
      } else {
        short4_t xv = *(const short4_t*)((const bf16*)C + off);
        float4 h4 = *(const float4*)&hook[off];
        float hk[4] = {h4.x, h4.y, h4.z, h4.w};
        short4_t pk;
#pragma unroll
        for (int rr = 0; rr < 4; ++rr)
          pk[rr] = f2bf(wmg * hk[rr] + omg * (bf2f(xv[rr]) + v[rr]));
        *(short4_t*)((bf16*)C + off) = pk;
      }
    }
  }

  if (FLN != 0) {
    // last-arrival fused LN over this 128-row panel of x (= C)
    __shared__ int lastf;
    __threadfence();
    if (tid == 0)
      lastf = (atomicAdd(&cnt[m0 >> 7], 1) == (int)gy - 1) ? 1 : 0;
    __syncthreads();
    if (lastf) {
      __threadfence();  // acquire: other tiles' x writes visible
      const bf16* xr = (const bf16*)C;
      for (int r2 = wave; r2 < 128; r2 += 4) {
        const int row = m0 + r2;
        if (row >= MR) break;
        const short8* xp = (const short8*)(xr + (size_t)row * ldc);
        short8 v0 = xp[lane * 2];
        short8 v1 = xp[lane * 2 + 1];
        float f[16];
        float s1 = 0.f, s2 = 0.f;
#pragma unroll
        for (int e = 0; e < 8; ++e) {
          f[e] = bf2f(v0[e]);
          f[8 + e] = bf2f(v1[e]);
        }
#pragma unroll
        for (int e = 0; e < 16; ++e) {
          s1 += f[e];
          s2 += f[e] * f[e];
        }
#pragma unroll
        for (int o = 32; o >= 1; o >>= 1) {
          s1 += __shfl_down(s1, o);
          s2 += __shfl_down(s2, o);
        }
        s1 = __shfl(s1, 0);
        s2 = __shfl(s2, 0);
        const float mu = s1 * (1.f / DM);
        const float rs = rsqrtf(s2 * (1.f / DM) - mu * mu + LNEPS);
        const int c0 = lane * 16;
        short8 o0, o1;
#pragma unroll
        for (int e = 0; e < 16; ++e) {
          float t = (f[e] - mu) * rs * lnw[c0 + e] + lnb[c0 + e];
          if (e < 8) o0[e] = f2bf(t);
          else o1[e - 8] = f2bf(t);
        }
        size_t orow = row;
        if (FLN == 2) orow = (size_t)(row & 63) * SL + (row >> 6);
        short8* op = (short8*)(lnout + orow * DM + c0);
        op[0] = o0;
        op[1] = o1;
      }
    }
  }
}

// ---------------- driver ----------------
extern "C" void kernel_launch(void* const* d_in, const int* in_sizes, int n_in,
                              void* d_out, int out_size, void* d_ws, size_t ws_size,
                              hipStream_t stream) {
  const float* hook = (const float*)d_in[0];
  const float* alpha = (const float*)d_in[1];
  const float* ipw = (const float*)d_in[2];
  const float* ipb = (const float*)d_in[3];
  const float* opw = (const float*)d_in[4];
  const float* opb = (const float*)d_in[5];
  const float* l1w = (const float*)d_in[6];
  const float* l1b = (const float*)d_in[7];
  const float* l2w = (const float*)d_in[8];
  const float* l2b = (const float*)d_in[9];
  const float* fcw = (const float*)d_in[10];
  const float* fcb = (const float*)d_in[11];
  const float* cpw = (const float*)d_in[12];
  const float* cpb = (const float*)d_in[13];
  const float* lpw = (const float*)d_in[14];
  const float* lpb = (const float*)d_in[15];
  const float* proj = (const float*)d_in[16];

  char* ws = (char*)d_ws;
  size_t off = 0;
  bf16* x = (bf16*)(ws + off); off += (size_t)MP * DM * 2;
  bf16* hbuf = (bf16*)(ws + off); off += (size_t)MP * DM * 2;
  bf16* qkv = (bf16*)(ws + off);
  bf16* mbuf = (bf16*)qkv;  // reuse qkv region for MLP intermediate
  off += (size_t)MP * 1024 * 2;
  bf16* obuf = (bf16*)(ws + off); off += (size_t)MP * DRED * 2;
  bf16* wq = (bf16*)(ws + off); off += (size_t)KBLK * 768 * DM * 2;
  bf16* wo = (bf16*)(ws + off); off += (size_t)KBLK * DM * DRED * 2;
  bf16* wfc = (bf16*)(ws + off); off += (size_t)KBLK * DM * DM * 2;
  bf16* wcp = (bf16*)(ws + off); off += (size_t)KBLK * DM * DM * 2;
  bf16* wpj = (bf16*)(ws + off); off += (size_t)768 * DM * 2;
  int* cnt = (int*)(ws + off); off += NCNT * 4;

  cast_all_kernel<<<9600, 256, 0, stream>>>(ipw, opw, fcw, cpw, proj,
                                            wq, wo, wfc, wcp, wpj, cnt);

  const dim3 gq(MP / 128, 768 / 128);   // N=768 grids: 774 wgs
  const dim3 gm(MP / 128, DM / 128);    // N=1024 grids: 1032 wgs

  for (int i = 0; i < KBLK; ++i) {
    if (i == 0)
      ln0_kernel<<<MR, 256, 0, stream>>>(hook, x, hbuf, l1w, l1b);
    // qkv = LN(x) @ ipw^T + ipb (bf16); hbuf produced by ln0 (i=0) or fused LN (i>0)
    gemm_kernel<3, 0><<<gq, 256, 0, stream>>>(hbuf, DM, wq + (size_t)i * 768 * DM, DM,
                                              ipb + i * 768, qkv, 768, DM, MR,
                                              nullptr, nullptr, 0,
                                              nullptr, nullptr, nullptr, nullptr);
    attn_mfma_kernel<<<BA * NHEAD, 256, 0, stream>>>(qkv, obuf);
    // x += attn_out @ opw^T + opb ; fused LN2 -> hbuf
    gemm_kernel<1, 1><<<gm, 256, 0, stream>>>(obuf, DRED, wo + (size_t)i * DM * DRED, DRED,
                                              opb + i * DM, x, DM, DRED, MR,
                                              nullptr, nullptr, 0,
                                              l2w + i * DM, l2b + i * DM, hbuf,
                                              cnt + (2 * i) * NPANEL);
    // mbuf = quickgelu(LN2(x) @ fcw^T + fcb)
    gemm_kernel<2, 0><<<gm, 256, 0, stream>>>(hbuf, DM, wfc + (size_t)i * DM * DM, DM,
                                              fcb + i * DM, mbuf, DM, DM, MR,
                                              nullptr, nullptr, 0,
                                              nullptr, nullptr, nullptr, nullptr);
    // x = [gate_{i+1}] (x + mbuf @ cpw^T + cpb) ; fused LN1(i+1) or LNpost -> hbuf
    if (i + 1 < KBLK)
      gemm_kernel<4, 1><<<gm, 256, 0, stream>>>(mbuf, DM, wcp + (size_t)i * DM * DM, DM,
                                                cpb + i * DM, x, DM, DM, MR,
                                                hook + (size_t)(i + 1) * MR * DM, alpha, i + 1,
                                                l1w + (i + 1) * DM, l1b + (i + 1) * DM, hbuf,
                                                cnt + (2 * i + 1) * NPANEL);
    else
      gemm_kernel<1, 2><<<gm, 256, 0, stream>>>(mbuf, DM, wcp + (size_t)i * DM * DM, DM,
                                                cpb + i * DM, x, DM, DM, MR,
                                                nullptr, nullptr, 0,
                                                lpw, lpb, hbuf,
                                                cnt + (2 * i + 1) * NPANEL);
  }
  // final projection from hbuf (LN_post already fused, transposed) -> d_out (fp32)
  gemm_kernel<0, 0><<<gq, 256, 0, stream>>>(hbuf, DM, wpj, DM, nullptr,
                                            (float*)d_out, 768, DM, MR,
                                            nullptr, nullptr, 0,
                                            nullptr, nullptr, nullptr, nullptr);
}

// Round 10
// 1702.282 us; speedup vs baseline: 3.0219x; 2.6008x over previous
//
#include <hip/hip_runtime.h>
#include <hip/hip_bf16.h>
#include <cstdint>
#include <cstddef>

// Problem constants
#define KBLK 6
#define SL 257
#define BA 64
#define DM 1024
#define NHEAD 16
#define DRED 256
#define HDM 16
#define MR (SL * BA)     // 16448 real rows
#define MP 16512         // 129 * 128 padded rows
#define LNEPS 1e-5f

typedef __hip_bfloat16 bf16;
typedef __attribute__((ext_vector_type(8))) short short8;
typedef __attribute__((ext_vector_type(4))) short short4_t;
typedef __attribute__((ext_vector_type(4))) float f32x4;

__device__ __forceinline__ void gld_lds16(const void* g, void* l) {
  __builtin_amdgcn_global_load_lds(
      (const __attribute__((address_space(1))) unsigned int*)g,
      (__attribute__((address_space(3))) unsigned int*)l, 16, 0, 0);
}

__device__ __forceinline__ float bf2f(short s) {
  bf16 t = *reinterpret_cast<bf16*>(&s);
  return __bfloat162float(t);
}
__device__ __forceinline__ short f2bf(float f) {
  bf16 t = __float2bfloat16(f);
  return *reinterpret_cast<short*>(&t);
}

// ---------------- fused weight casts (one launch) ----------------
__global__ __launch_bounds__(256) void cast_all_kernel(
    const float* __restrict__ ipw, const float* __restrict__ opw,
    const float* __restrict__ fcw, const float* __restrict__ cpw,
    const float* __restrict__ proj,
    bf16* __restrict__ wq, bf16* __restrict__ wo, bf16* __restrict__ wfc,
    bf16* __restrict__ wcp, bf16* __restrict__ wpj) {
  const int blk = blockIdx.x;
  const int tid = threadIdx.x;
  const float* src;
  bf16* dst;
  int base;
  bool tr = false;
  if (blk < 2304)      { src = ipw; dst = wq;  base = blk * 2048; }
  else if (blk < 3072) { src = opw; dst = wo;  base = (blk - 2304) * 2048; }
  else if (blk < 6144) { src = fcw; dst = wfc; base = (blk - 3072) * 2048; }
  else if (blk < 9216) { src = cpw; dst = wcp; base = (blk - 6144) * 2048; }
  else                 { src = proj; dst = wpj; base = (blk - 9216) * 2048; tr = true; }
  const int idx = base + tid * 8;
  short8 o;
  if (!tr) {
    float4 a = *(const float4*)(src + idx);
    float4 b = *(const float4*)(src + idx + 4);
    o[0] = f2bf(a.x); o[1] = f2bf(a.y); o[2] = f2bf(a.z); o[3] = f2bf(a.w);
    o[4] = f2bf(b.x); o[5] = f2bf(b.y); o[6] = f2bf(b.z); o[7] = f2bf(b.w);
  } else {
    int n = idx >> 10, k = idx & 1023;
#pragma unroll
    for (int e = 0; e < 8; ++e) o[e] = f2bf(src[(size_t)(k + e) * 768 + n]);
  }
  *(short8*)(dst + idx) = o;
}

// ---------------- LayerNorm ----------------
// MODE 0: x = bf16(hook); LN(hook) -> hout
// MODE 2: LN(x) -> hout
// MODE 3: LN(x) -> hout at transposed row (b*SL+s)  [ln_post]
template <int MODE>
__global__ __launch_bounds__(256) void ln_kernel(
    const float* __restrict__ hook,
    bf16* __restrict__ x, bf16* __restrict__ hout,
    const float* __restrict__ w, const float* __restrict__ bb) {
  const int row = blockIdx.x;
  const int tid = threadIdx.x;
  const size_t base = (size_t)row * DM + tid * 4;
  float vals[4];
  if (MODE == 0) {
    float4 v = *(const float4*)(hook + base);
    vals[0] = v.x; vals[1] = v.y; vals[2] = v.z; vals[3] = v.w;
    short4_t pk;
#pragma unroll
    for (int j = 0; j < 4; ++j) pk[j] = f2bf(vals[j]);
    *(short4_t*)&x[base] = pk;
  } else {
    short4_t xv = *(const short4_t*)&x[base];
#pragma unroll
    for (int j = 0; j < 4; ++j) vals[j] = bf2f(xv[j]);
  }
  float s1 = vals[0] + vals[1] + vals[2] + vals[3];
  float s2 = vals[0] * vals[0] + vals[1] * vals[1] + vals[2] * vals[2] + vals[3] * vals[3];
#pragma unroll
  for (int o = 32; o >= 1; o >>= 1) {
    s1 += __shfl_down(s1, o);
    s2 += __shfl_down(s2, o);
  }
  __shared__ float red[8];
  if ((tid & 63) == 0) {
    red[tid >> 6] = s1;
    red[4 + (tid >> 6)] = s2;
  }
  __syncthreads();
  s1 = red[0] + red[1] + red[2] + red[3];
  s2 = red[4] + red[5] + red[6] + red[7];
  const float mu = s1 * (1.f / DM);
  const float rs = rsqrtf(s2 * (1.f / DM) - mu * mu + LNEPS);
  size_t orow = row;
  if (MODE == 3) {
    int s = row >> 6, b2 = row & 63;
    orow = (size_t)b2 * SL + s;
  }
  const int c = tid * 4;
  short4_t pk;
#pragma unroll
  for (int j = 0; j < 4; ++j)
    pk[j] = f2bf((vals[j] - mu) * rs * w[c + j] + bb[c + j]);
  *(short4_t*)((char*)hout + (orow * DM + c) * 2) = pk;
}

// ---------------- MFMA attention (validated) ----------------
__global__ __launch_bounds__(256) void attn_mfma_kernel(const bf16* __restrict__ qkv,
                                                        bf16* __restrict__ obuf) {
  __shared__ __align__(16) short ql[272][24];
  __shared__ __align__(16) short kl[272][24];
  __shared__ __align__(16) short vt[16][296];
  __shared__ __align__(16) short pl[4][16][40];
  const int bh = blockIdx.x;
  const int b = bh >> 4, h = bh & 15;
  const int tid = threadIdx.x;
  const int wave = tid >> 6, lane = tid & 63;
  const int g = lane >> 4, qi = lane & 15;

  const short8 zero8 = {0, 0, 0, 0, 0, 0, 0, 0};
  const f32x4 fzero = {0.f, 0.f, 0.f, 0.f};

  for (int task = tid; task < 1632; task += 256) {
    int a, rem;
    if (task < 544) { a = 0; rem = task; }
    else if (task < 1088) { a = 1; rem = task - 544; }
    else { a = 2; rem = task - 1088; }
    int row = rem >> 1, half = rem & 1;
    short8 v = zero8;
    if (row < SL)
      v = *(const short8*)((const short*)qkv + (size_t)(row * BA + b) * 768 + a * 256 + h * 16 + half * 8);
    if (a == 0) *(short8*)&ql[row][half * 8] = v;
    else if (a == 1) *(short8*)&kl[row][half * 8] = v;
    else {
#pragma unroll
      for (int j = 0; j < 8; ++j) vt[half * 8 + j][row] = v[j];
    }
  }
  for (int i = tid; i < 16 * 24; i += 256) vt[i / 24][272 + (i % 24)] = 0;
  __syncthreads();

  for (int t = wave; t < 17; t += 4) {
    short8 bq = zero8;
    if (g < 2) bq = *(const short8*)&ql[t * 16 + qi][g * 8];

    f32x4 st[18];
#pragma unroll
    for (int t2 = 0; t2 < 17; ++t2) {
      short8 ak = zero8;
      if (g < 2) ak = *(const short8*)&kl[t2 * 16 + qi][g * 8];
      st[t2] = __builtin_amdgcn_mfma_f32_16x16x32_bf16(ak, bq, fzero, 0, 0, 0);
    }
    float mx = -1e30f;
#pragma unroll
    for (int t2 = 0; t2 < 17; ++t2) {
#pragma unroll
      for (int r = 0; r < 4; ++r) {
        int s = t2 * 16 + g * 4 + r;
        float v = (s <= 256) ? st[t2][r] * 0.25f : -1e30f;
        st[t2][r] = v;
        mx = fmaxf(mx, v);
      }
    }
    mx = fmaxf(mx, __shfl_xor(mx, 16));
    mx = fmaxf(mx, __shfl_xor(mx, 32));
    float ls = 0.f;
#pragma unroll
    for (int t2 = 0; t2 < 17; ++t2) {
#pragma unroll
      for (int r = 0; r < 4; ++r) {
        float p = __expf(st[t2][r] - mx);
        st[t2][r] = p;
        ls += p;
      }
    }
    ls += __shfl_xor(ls, 16);
    ls += __shfl_xor(ls, 32);
    const float inv = 1.f / ls;
#pragma unroll
    for (int t2 = 0; t2 < 17; ++t2)
#pragma unroll
      for (int r = 0; r < 4; ++r) st[t2][r] *= inv;
    st[17] = fzero;

    f32x4 acc = fzero;
#pragma unroll
    for (int tt = 0; tt < 9; ++tt) {
#pragma unroll
      for (int hh = 0; hh < 2; ++hh) {
        int t2 = tt * 2 + hh;
        short4_t pk;
#pragma unroll
        for (int r = 0; r < 4; ++r) pk[r] = f2bf(st[t2][r]);
        *(short4_t*)&pl[wave][qi][hh * 16 + g * 4] = pk;
      }
      short8 pa = *(const short8*)&pl[wave][qi][g * 8];
      short8 bv = *(const short8*)&vt[qi][tt * 32 + g * 8];
      acc = __builtin_amdgcn_mfma_f32_16x16x32_bf16(pa, bv, acc, 0, 0, 0);
    }
#pragma unroll
    for (int r = 0; r < 4; ++r) {
      int qr = t * 16 + g * 4 + r;
      if (qr < SL)
        obuf[(size_t)(qr * BA + b) * DRED + h * 16 + qi] = __float2bfloat16(acc[r]);
    }
  }
}

// ---------------- unified 128x128 GEMM (round-7 validated), compile-time K & grid ----------------
// C(M,N) = A(M,K) * Bw(N,K)^T + bias.  Swapped mfma operands -> vectorized epilogue.
// EPI 0 fp32 write | 1 bf16 RMW += | 2 bf16 quickgelu | 3 bf16 write | 4 gated residual RMW
// KDIM in {1024, 256}; NT = N/128 in {6, 8}. Grid = dim3(129, NT).
template <int EPI, int KDIM, int NT>
__global__ __launch_bounds__(256, 4) void gemm_kernel(
    const bf16* __restrict__ A, int lda,
    const bf16* __restrict__ Bw, int ldb,
    const float* __restrict__ bias,
    void* __restrict__ C, int ldc,
    const float* __restrict__ hook, const float* __restrict__ alphap, int kidx) {
  __shared__ char lds[32768];  // A 16KB | B 16KB, BK=64
  const int tid = threadIdx.x;
  const int wave = tid >> 6, lane = tid & 63;
  const int lrow = lane & 15, lk = lane >> 4;
  const int wr = wave >> 1, wc = wave & 1;

  // XCD-aware bijective swizzle (m204), n-fastest decomposition, all constexpr
  constexpr int nwg = 129 * NT;
  constexpr int q = nwg >> 3, r = nwg & 7;
  const int orig = blockIdx.y * 129 + blockIdx.x;
  const int xcd = orig & 7, idx = orig >> 3;
  const int wgid = (xcd < r ? xcd * (q + 1) : r * (q + 1) + (xcd - r) * q) + idx;
  const int m0 = (wgid / NT) * 128;
  const int n0 = (wgid % NT) * 128;

  f32x4 acc[4][4];
  const f32x4 zero = {0.f, 0.f, 0.f, 0.f};
#pragma unroll
  for (int i = 0; i < 4; ++i)
#pragma unroll
    for (int j = 0; j < 4; ++j) acc[i][j] = zero;

  constexpr int nk = KDIM >> 6;

  for (int kt = 0; kt < nk; ++kt) {
    const int k0 = kt << 6;
#pragma unroll
    for (int j = 0; j < 4; ++j) {
      int c = wave * 256 + j * 64 + lane;
      int row = c >> 3, segp = c & 7;
      int seg = segp ^ (row & 7);
      gld_lds16(A + (size_t)(m0 + row) * lda + k0 + seg * 8, &lds[c * 16]);
      gld_lds16(Bw + (size_t)(n0 + row) * ldb + k0 + seg * 8, &lds[16384 + c * 16]);
    }
    __syncthreads();
#pragma unroll
    for (int kh = 0; kh < 2; ++kh) {
      short8 af[4], bfr[4];
#pragma unroll
      for (int i = 0; i < 4; ++i) {
        int rr = wr * 64 + i * 16 + lrow;
        int seg = kh * 4 + lk;
        af[i] = *(const short8*)(lds + rr * 128 + ((seg ^ (rr & 7)) << 4));
      }
#pragma unroll
      for (int j = 0; j < 4; ++j) {
        int rr = wc * 64 + j * 16 + lrow;
        int seg = kh * 4 + lk;
        bfr[j] = *(const short8*)(lds + 16384 + rr * 128 + ((seg ^ (rr & 7)) << 4));
      }
      // swapped operands: D rows = B-tile cols, D cols (lane&15) = A-tile rows
#pragma unroll
      for (int i = 0; i < 4; ++i)
#pragma unroll
        for (int j = 0; j < 4; ++j)
          acc[i][j] = __builtin_amdgcn_mfma_f32_16x16x32_bf16(bfr[j], af[i], acc[i][j], 0, 0, 0);
    }
    __syncthreads();
  }

  // epilogue: lane holds row = ...+i*16+lrow, cols = ...+j*16+lk*4 .. +3
  float wmg = 0.f, omg = 0.f;
  if (EPI == 4) {
    wmg = 1.f / (1.f + __expf(-alphap[kidx] * 10.f));
    omg = 1.f - wmg;
  }
  // bias hoist: col(j) independent of i
  float4 bj[4];
#pragma unroll
  for (int j = 0; j < 4; ++j) {
    const int col = n0 + wc * 64 + j * 16 + lk * 4;
    bj[j] = bias ? *(const float4*)&bias[col] : float4{0.f, 0.f, 0.f, 0.f};
  }
#pragma unroll
  for (int i = 0; i < 4; ++i) {
    const int row = m0 + wr * 64 + i * 16 + lrow;
    if (row >= MR) continue;
#pragma unroll
    for (int j = 0; j < 4; ++j) {
      const int col = n0 + wc * 64 + j * 16 + lk * 4;
      const size_t off = (size_t)row * ldc + col;
      const float bv[4] = {bj[j].x, bj[j].y, bj[j].z, bj[j].w};
      float v[4];
#pragma unroll
      for (int rr = 0; rr < 4; ++rr) v[rr] = acc[i][j][rr] + bv[rr];
      if (EPI == 0) {
        float4 o4 = {v[0], v[1], v[2], v[3]};
        *(float4*)((float*)C + off) = o4;
      } else if (EPI == 2) {
        short4_t pk;
#pragma unroll
        for (int rr = 0; rr < 4; ++rr)
          pk[rr] = f2bf(v[rr] / (1.f + __expf(-1.702f * v[rr])));
        *(short4_t*)((bf16*)C + off) = pk;
      } else if (EPI == 3) {
        short4_t pk;
#pragma unroll
        for (int rr = 0; rr < 4; ++rr) pk[rr] = f2bf(v[rr]);
        *(short4_t*)((bf16*)C + off) = pk;
      } else if (EPI == 1) {
        short4_t xv = *(const short4_t*)((const bf16*)C + off);
        short4_t pk;
#pragma unroll
        for (int rr = 0; rr < 4; ++rr) pk[rr] = f2bf(bf2f(xv[rr]) + v[rr]);
        *(short4_t*)((bf16*)C + off) = pk;
      } else {  // EPI 4
        short4_t xv = *(const short4_t*)((const bf16*)C + off);
        float4 h4 = *(const float4*)&hook[off];
        float hk[4] = {h4.x, h4.y, h4.z, h4.w};
        short4_t pk;
#pragma unroll
        for (int rr = 0; rr < 4; ++rr)
          pk[rr] = f2bf(wmg * hk[rr] + omg * (bf2f(xv[rr]) + v[rr]));
        *(short4_t*)((bf16*)C + off) = pk;
      }
    }
  }
}

// ---------------- driver ----------------
extern "C" void kernel_launch(void* const* d_in, const int* in_sizes, int n_in,
                              void* d_out, int out_size, void* d_ws, size_t ws_size,
                              hipStream_t stream) {
  const float* hook = (const float*)d_in[0];
  const float* alpha = (const float*)d_in[1];
  const float* ipw = (const float*)d_in[2];
  const float* ipb = (const float*)d_in[3];
  const float* opw = (const float*)d_in[4];
  const float* opb = (const float*)d_in[5];
  const float* l1w = (const float*)d_in[6];
  const float* l1b = (const float*)d_in[7];
  const float* l2w = (const float*)d_in[8];
  const float* l2b = (const float*)d_in[9];
  const float* fcw = (const float*)d_in[10];
  const float* fcb = (const float*)d_in[11];
  const float* cpw = (const float*)d_in[12];
  const float* cpb = (const float*)d_in[13];
  const float* lpw = (const float*)d_in[14];
  const float* lpb = (const float*)d_in[15];
  const float* proj = (const float*)d_in[16];

  char* ws = (char*)d_ws;
  size_t off = 0;
  bf16* x = (bf16*)(ws + off); off += (size_t)MP * DM * 2;
  bf16* hbuf = (bf16*)(ws + off); off += (size_t)MP * DM * 2;
  bf16* qkv = (bf16*)(ws + off);
  bf16* mbuf = (bf16*)qkv;  // reuse qkv region for MLP intermediate
  off += (size_t)MP * 1024 * 2;
  bf16* obuf = (bf16*)(ws + off); off += (size_t)MP * DRED * 2;
  bf16* wq = (bf16*)(ws + off); off += (size_t)KBLK * 768 * DM * 2;
  bf16* wo = (bf16*)(ws + off); off += (size_t)KBLK * DM * DRED * 2;
  bf16* wfc = (bf16*)(ws + off); off += (size_t)KBLK * DM * DM * 2;
  bf16* wcp = (bf16*)(ws + off); off += (size_t)KBLK * DM * DM * 2;
  bf16* wpj = (bf16*)(ws + off); off += (size_t)768 * DM * 2;

  cast_all_kernel<<<9600, 256, 0, stream>>>(ipw, opw, fcw, cpw, proj,
                                            wq, wo, wfc, wcp, wpj);

  const dim3 gq(129, 6);   // N=768 grids (qkv, final proj): 774 wgs
  const dim3 gm(129, 8);   // N=1024 grids: 1032 wgs

  for (int i = 0; i < KBLK; ++i) {
    if (i == 0)
      ln_kernel<0><<<MR, 256, 0, stream>>>(hook, x, hbuf, l1w, l1b);
    else
      ln_kernel<2><<<MR, 256, 0, stream>>>(nullptr, x, hbuf, l1w + i * DM, l1b + i * DM);
    // qkv = LN1(x) @ ipw^T + ipb (bf16)
    gemm_kernel<3, 1024, 6><<<gq, 256, 0, stream>>>(hbuf, DM, wq + (size_t)i * 768 * DM, DM,
                                                    ipb + i * 768, qkv, 768,
                                                    nullptr, nullptr, 0);
    attn_mfma_kernel<<<BA * NHEAD, 256, 0, stream>>>(qkv, obuf);
    // x += attn_out @ opw^T + opb   (in-place RMW, disjoint tiles)
    gemm_kernel<1, 256, 8><<<gm, 256, 0, stream>>>(obuf, DRED, wo + (size_t)i * DM * DRED, DRED,
                                                   opb + i * DM, x, DM,
                                                   nullptr, nullptr, 0);
    ln_kernel<2><<<MR, 256, 0, stream>>>(nullptr, x, hbuf, l2w + i * DM, l2b + i * DM);
    // mbuf = quickgelu(LN2(x) @ fcw^T + fcb)
    gemm_kernel<2, 1024, 8><<<gm, 256, 0, stream>>>(hbuf, DM, wfc + (size_t)i * DM * DM, DM,
                                                    fcb + i * DM, mbuf, DM,
                                                    nullptr, nullptr, 0);
    // x = [gate with next block's hook] (x + mbuf @ cpw^T + cpb)  (in-place RMW)
    if (i + 1 < KBLK)
      gemm_kernel<4, 1024, 8><<<gm, 256, 0, stream>>>(mbuf, DM, wcp + (size_t)i * DM * DM, DM,
                                                      cpb + i * DM, x, DM,
                                                      hook + (size_t)(i + 1) * MR * DM, alpha, i + 1);
    else
      gemm_kernel<1, 1024, 8><<<gm, 256, 0, stream>>>(mbuf, DM, wcp + (size_t)i * DM * DM, DM,
                                                      cpb + i * DM, x, DM,
                                                      nullptr, nullptr, 0);
  }
  // final: LN_post (transposed to (B,S,D)) then @ proj -> d_out (fp32)
  ln_kernel<3><<<MR, 256, 0, stream>>>(nullptr, x, hbuf, lpw, lpb);
  gemm_kernel<0, 1024, 6><<<gq, 256, 0, stream>>>(hbuf, DM, wpj, DM, nullptr,
                                                  (float*)d_out, 768,
                                                  nullptr, nullptr, 0);
}

// Round 11
// 1606.913 us; speedup vs baseline: 3.2012x; 1.0593x over previous
//
#include <hip/hip_runtime.h>
#include <hip/hip_bf16.h>
#include <cstdint>
#include <cstddef>

// Problem constants
#define KBLK 6
#define SL 257
#define BA 64
#define DM 1024
#define NHEAD 16
#define DRED 256
#define HDM 16
#define MR (SL * BA)     // 16448 real rows
#define MP 16512         // 129 * 128 padded rows
#define LNEPS 1e-5f

typedef __hip_bfloat16 bf16;
typedef __attribute__((ext_vector_type(8))) short short8;
typedef __attribute__((ext_vector_type(4))) short short4_t;
typedef __attribute__((ext_vector_type(4))) float f32x4;

__device__ __forceinline__ void gld_lds16(const void* g, void* l) {
  __builtin_amdgcn_global_load_lds(
      (const __attribute__((address_space(1))) unsigned int*)g,
      (__attribute__((address_space(3))) unsigned int*)l, 16, 0, 0);
}

__device__ __forceinline__ float bf2f(short s) {
  bf16 t = *reinterpret_cast<bf16*>(&s);
  return __bfloat162float(t);
}
__device__ __forceinline__ short f2bf(float f) {
  bf16 t = __float2bfloat16(f);
  return *reinterpret_cast<short*>(&t);
}

// ---------------- fused weight casts + LN folding + row-sum precompute ----------------
// wq  <- l1w ∘ ipw   (+ S'=row sums, BB = l1b·row + ipb)
// wfc <- l2w ∘ fcw   (+ S', BB = l2b·row + fcb)
// wpj <- lpw ∘ proj^T (+ S', BB = lpb·row)
// wo, wcp: plain cast (their A-operands are not LN outputs).
__global__ __launch_bounds__(256) void cast_all_kernel(
    const float* __restrict__ ipw, const float* __restrict__ opw,
    const float* __restrict__ fcw, const float* __restrict__ cpw,
    const float* __restrict__ proj,
    const float* __restrict__ l1w, const float* __restrict__ l1b,
    const float* __restrict__ l2w, const float* __restrict__ l2b,
    const float* __restrict__ lpw, const float* __restrict__ lpb,
    const float* __restrict__ ipb, const float* __restrict__ fcb,
    bf16* __restrict__ wq, bf16* __restrict__ wo, bf16* __restrict__ wfc,
    bf16* __restrict__ wcp, bf16* __restrict__ wpj,
    float* __restrict__ sq_q, float* __restrict__ bb_q,
    float* __restrict__ sq_fc, float* __restrict__ bb_fc,
    float* __restrict__ sq_pj, float* __restrict__ bb_pj) {
  const int blk = blockIdx.x;
  const int tid = threadIdx.x;
  float sp = 0.f, bbp = 0.f;
  float* sqDst = nullptr;
  float* bbDst = nullptr;
  const float* bflat = nullptr;
  int grow = 0;

  if (blk < 2304) {  // wq: 4608 rows x 1024, folded with l1
    const int base = blk * 2048, idx = base + tid * 8;
    grow = base >> 10;
    const int rowt = idx >> 10, col = idx & 1023;
    const int tb = rowt / 768;
    const float* lw = l1w + tb * DM;
    const float* lb = l1b + tb * DM;
    float4 a = *(const float4*)(ipw + idx);
    float4 b = *(const float4*)(ipw + idx + 4);
    float v[8] = {a.x, a.y, a.z, a.w, b.x, b.y, b.z, b.w};
    short8 o;
#pragma unroll
    for (int e = 0; e < 8; ++e) {
      float f = v[e] * lw[col + e];
      sp += f;
      bbp += lb[col + e] * v[e];
      o[e] = f2bf(f);
    }
    *(short8*)(wq + idx) = o;
    sqDst = sq_q; bbDst = bb_q; bflat = ipb;
  } else if (blk < 3072) {  // wo plain
    const int base = (blk - 2304) * 2048, idx = base + tid * 8;
    float4 a = *(const float4*)(opw + idx);
    float4 b = *(const float4*)(opw + idx + 4);
    short8 o;
    o[0] = f2bf(a.x); o[1] = f2bf(a.y); o[2] = f2bf(a.z); o[3] = f2bf(a.w);
    o[4] = f2bf(b.x); o[5] = f2bf(b.y); o[6] = f2bf(b.z); o[7] = f2bf(b.w);
    *(short8*)(wo + idx) = o;
  } else if (blk < 6144) {  // wfc: 6144 rows x 1024, folded with l2
    const int base = (blk - 3072) * 2048, idx = base + tid * 8;
    grow = base >> 10;
    const int rowt = idx >> 10, col = idx & 1023;
    const int tb = rowt >> 10;
    const float* lw = l2w + tb * DM;
    const float* lb = l2b + tb * DM;
    float4 a = *(const float4*)(fcw + idx);
    float4 b = *(const float4*)(fcw + idx + 4);
    float v[8] = {a.x, a.y, a.z, a.w, b.x, b.y, b.z, b.w};
    short8 o;
#pragma unroll
    for (int e = 0; e < 8; ++e) {
      float f = v[e] * lw[col + e];
      sp += f;
      bbp += lb[col + e] * v[e];
      o[e] = f2bf(f);
    }
    *(short8*)(wfc + idx) = o;
    sqDst = sq_fc; bbDst = bb_fc; bflat = fcb;
  } else if (blk < 9216) {  // wcp plain
    const int base = (blk - 6144) * 2048, idx = base + tid * 8;
    float4 a = *(const float4*)(cpw + idx);
    float4 b = *(const float4*)(cpw + idx + 4);
    short8 o;
    o[0] = f2bf(a.x); o[1] = f2bf(a.y); o[2] = f2bf(a.z); o[3] = f2bf(a.w);
    o[4] = f2bf(b.x); o[5] = f2bf(b.y); o[6] = f2bf(b.z); o[7] = f2bf(b.w);
    *(short8*)(wcp + idx) = o;
  } else {  // wpj: 768 rows x 1024, transposed gather, folded with lnpost
    const int base = (blk - 9216) * 2048, idx = base + tid * 8;
    grow = base >> 10;
    const int n = idx >> 10, k0 = idx & 1023;
    short8 o;
#pragma unroll
    for (int e = 0; e < 8; ++e) {
      float v = proj[(size_t)(k0 + e) * 768 + n];
      float f = v * lpw[k0 + e];
      sp += f;
      bbp += lpb[k0 + e] * v;
      o[e] = f2bf(f);
    }
    *(short8*)(wpj + idx) = o;
    sqDst = sq_pj; bbDst = bb_pj; bflat = nullptr;
  }

  if (sqDst) {
    // rows: threads [0,128) -> grow, [128,256) -> grow+1 (waves 0,1 | 2,3)
#pragma unroll
    for (int o = 32; o >= 1; o >>= 1) {
      sp += __shfl_down(sp, o);
      bbp += __shfl_down(bbp, o);
    }
    __shared__ float wred[4][2];
    const int wave = tid >> 6;
    if ((tid & 63) == 0) {
      wred[wave][0] = sp;
      wred[wave][1] = bbp;
    }
    __syncthreads();
    if (tid == 0) {
      sqDst[grow] = wred[0][0] + wred[1][0];
      bbDst[grow] = wred[0][1] + wred[1][1] + (bflat ? bflat[grow] : 0.f);
    } else if (tid == 128) {
      sqDst[grow + 1] = wred[2][0] + wred[3][0];
      bbDst[grow + 1] = wred[2][1] + wred[3][1] + (bflat ? bflat[grow + 1] : 0.f);
    }
  }
}

// ---------------- stat0: x = bf16(hook), row stats of hook -> stats12 ----------------
__global__ __launch_bounds__(256) void stat0_kernel(
    const float* __restrict__ hook, bf16* __restrict__ x,
    float2* __restrict__ st12) {
  const int row = blockIdx.x;
  const int tid = threadIdx.x;
  const size_t base = (size_t)row * DM + tid * 4;
  float4 v = *(const float4*)(hook + base);
  short4_t pk;
  pk[0] = f2bf(v.x); pk[1] = f2bf(v.y); pk[2] = f2bf(v.z); pk[3] = f2bf(v.w);
  *(short4_t*)&x[base] = pk;
  float s1 = v.x + v.y + v.z + v.w;
  float s2 = v.x * v.x + v.y * v.y + v.z * v.z + v.w * v.w;
#pragma unroll
  for (int o = 32; o >= 1; o >>= 1) {
    s1 += __shfl_down(s1, o);
    s2 += __shfl_down(s2, o);
  }
  __shared__ float red[8];
  if ((tid & 63) == 0) {
    red[tid >> 6] = s1;
    red[4 + (tid >> 6)] = s2;
  }
  __syncthreads();
  if (tid == 0) {
    float t1 = red[0] + red[1] + red[2] + red[3];
    float t2 = red[4] + red[5] + red[6] + red[7];
    st12[row] = make_float2(t1, t2);
  }
}

// ---------------- MFMA attention (validated, unchanged) ----------------
__global__ __launch_bounds__(256) void attn_mfma_kernel(const bf16* __restrict__ qkv,
                                                        bf16* __restrict__ obuf) {
  __shared__ __align__(16) short ql[272][24];
  __shared__ __align__(16) short kl[272][24];
  __shared__ __align__(16) short vt[16][296];
  __shared__ __align__(16) short pl[4][16][40];
  const int bh = blockIdx.x;
  const int b = bh >> 4, h = bh & 15;
  const int tid = threadIdx.x;
  const int wave = tid >> 6, lane = tid & 63;
  const int g = lane >> 4, qi = lane & 15;

  const short8 zero8 = {0, 0, 0, 0, 0, 0, 0, 0};
  const f32x4 fzero = {0.f, 0.f, 0.f, 0.f};

  for (int task = tid; task < 1632; task += 256) {
    int a, rem;
    if (task < 544) { a = 0; rem = task; }
    else if (task < 1088) { a = 1; rem = task - 544; }
    else { a = 2; rem = task - 1088; }
    int row = rem >> 1, half = rem & 1;
    short8 v = zero8;
    if (row < SL)
      v = *(const short8*)((const short*)qkv + (size_t)(row * BA + b) * 768 + a * 256 + h * 16 + half * 8);
    if (a == 0) *(short8*)&ql[row][half * 8] = v;
    else if (a == 1) *(short8*)&kl[row][half * 8] = v;
    else {
#pragma unroll
      for (int j = 0; j < 8; ++j) vt[half * 8 + j][row] = v[j];
    }
  }
  for (int i = tid; i < 16 * 24; i += 256) vt[i / 24][272 + (i % 24)] = 0;
  __syncthreads();

  for (int t = wave; t < 17; t += 4) {
    short8 bq = zero8;
    if (g < 2) bq = *(const short8*)&ql[t * 16 + qi][g * 8];

    f32x4 st[18];
#pragma unroll
    for (int t2 = 0; t2 < 17; ++t2) {
      short8 ak = zero8;
      if (g < 2) ak = *(const short8*)&kl[t2 * 16 + qi][g * 8];
      st[t2] = __builtin_amdgcn_mfma_f32_16x16x32_bf16(ak, bq, fzero, 0, 0, 0);
    }
    float mx = -1e30f;
#pragma unroll
    for (int t2 = 0; t2 < 17; ++t2) {
#pragma unroll
      for (int r = 0; r < 4; ++r) {
        int s = t2 * 16 + g * 4 + r;
        float v = (s <= 256) ? st[t2][r] * 0.25f : -1e30f;
        st[t2][r] = v;
        mx = fmaxf(mx, v);
      }
    }
    mx = fmaxf(mx, __shfl_xor(mx, 16));
    mx = fmaxf(mx, __shfl_xor(mx, 32));
    float ls = 0.f;
#pragma unroll
    for (int t2 = 0; t2 < 17; ++t2) {
#pragma unroll
      for (int r = 0; r < 4; ++r) {
        float p = __expf(st[t2][r] - mx);
        st[t2][r] = p;
        ls += p;
      }
    }
    ls += __shfl_xor(ls, 16);
    ls += __shfl_xor(ls, 32);
    const float inv = 1.f / ls;
#pragma unroll
    for (int t2 = 0; t2 < 17; ++t2)
#pragma unroll
      for (int r = 0; r < 4; ++r) st[t2][r] *= inv;
    st[17] = fzero;

    f32x4 acc = fzero;
#pragma unroll
    for (int tt = 0; tt < 9; ++tt) {
#pragma unroll
      for (int hh = 0; hh < 2; ++hh) {
        int t2 = tt * 2 + hh;
        short4_t pk;
#pragma unroll
        for (int r = 0; r < 4; ++r) pk[r] = f2bf(st[t2][r]);
        *(short4_t*)&pl[wave][qi][hh * 16 + g * 4] = pk;
      }
      short8 pa = *(const short8*)&pl[wave][qi][g * 8];
      short8 bv = *(const short8*)&vt[qi][tt * 32 + g * 8];
      acc = __builtin_amdgcn_mfma_f32_16x16x32_bf16(pa, bv, acc, 0, 0, 0);
    }
#pragma unroll
    for (int r = 0; r < 4; ++r) {
      int qr = t * 16 + g * 4 + r;
      if (qr < SL)
        obuf[(size_t)(qr * BA + b) * DRED + h * 16 + qi] = __float2bfloat16(acc[r]);
    }
  }
}

// ---------------- unified 128x128 GEMM (validated mainloop) ----------------
// EPI 5: bf16 out = rs*acc - mu*rs*S'[n] + BB[n]                (fused-LN consumer, qkv)
// EPI 6: bf16 quickgelu(same)                                   (fc)
// EPI 7: fp32 out at transposed row (LN_post consumer, final proj)
// EPI 8: bf16 RMW C += acc + bias; emit row stats               (op / cproj last)
// EPI 9: bf16 C = wm*hook + (1-wm)*(C + acc + bias); emit stats (cproj gated)
template <int EPI, int KDIM, int NT>
__global__ __launch_bounds__(256, 4) void gemm_kernel(
    const bf16* __restrict__ A, int lda,
    const bf16* __restrict__ Bw, int ldb,
    const float* __restrict__ bias,
    void* __restrict__ C, int ldc,
    const float* __restrict__ hook, const float* __restrict__ alphap, int kidx,
    const float2* __restrict__ statsIn,
    const float* __restrict__ sarr, const float* __restrict__ barr,
    float2* __restrict__ statsOut) {
  __shared__ char lds[32768];  // A 16KB | B 16KB, BK=64
  const int tid = threadIdx.x;
  const int wave = tid >> 6, lane = tid & 63;
  const int lrow = lane & 15, lk = lane >> 4;
  const int wr = wave >> 1, wc = wave & 1;

  constexpr int nwg = 129 * NT;
  constexpr int q = nwg >> 3, r = nwg & 7;
  const int orig = blockIdx.y * 129 + blockIdx.x;
  const int xcd = orig & 7, idx = orig >> 3;
  const int wgid = (xcd < r ? xcd * (q + 1) : r * (q + 1) + (xcd - r) * q) + idx;
  const int m0 = (wgid / NT) * 128;
  const int n0 = (wgid % NT) * 128;

  f32x4 acc[4][4];
  const f32x4 zero = {0.f, 0.f, 0.f, 0.f};
#pragma unroll
  for (int i = 0; i < 4; ++i)
#pragma unroll
    for (int j = 0; j < 4; ++j) acc[i][j] = zero;

  constexpr int nk = KDIM >> 6;

  for (int kt = 0; kt < nk; ++kt) {
    const int k0 = kt << 6;
#pragma unroll
    for (int j = 0; j < 4; ++j) {
      int c = wave * 256 + j * 64 + lane;
      int row = c >> 3, segp = c & 7;
      int seg = segp ^ (row & 7);
      gld_lds16(A + (size_t)(m0 + row) * lda + k0 + seg * 8, &lds[c * 16]);
      gld_lds16(Bw + (size_t)(n0 + row) * ldb + k0 + seg * 8, &lds[16384 + c * 16]);
    }
    __syncthreads();
#pragma unroll
    for (int kh = 0; kh < 2; ++kh) {
      short8 af[4], bfr[4];
#pragma unroll
      for (int i = 0; i < 4; ++i) {
        int rr = wr * 64 + i * 16 + lrow;
        int seg = kh * 4 + lk;
        af[i] = *(const short8*)(lds + rr * 128 + ((seg ^ (rr & 7)) << 4));
      }
#pragma unroll
      for (int j = 0; j < 4; ++j) {
        int rr = wc * 64 + j * 16 + lrow;
        int seg = kh * 4 + lk;
        bfr[j] = *(const short8*)(lds + 16384 + rr * 128 + ((seg ^ (rr & 7)) << 4));
      }
      // swapped operands: lane's 4 acc elems are column-consecutive
#pragma unroll
      for (int i = 0; i < 4; ++i)
#pragma unroll
        for (int j = 0; j < 4; ++j)
          acc[i][j] = __builtin_amdgcn_mfma_f32_16x16x32_bf16(bfr[j], af[i], acc[i][j], 0, 0, 0);
    }
    __syncthreads();
  }

  float wmg = 0.f, omg = 0.f;
  if (EPI == 9) {
    wmg = 1.f / (1.f + __expf(-alphap[kidx] * 10.f));
    omg = 1.f - wmg;
  }

#pragma unroll
  for (int i = 0; i < 4; ++i) {
    const int row = m0 + wr * 64 + i * 16 + lrow;
    if (row >= MR) continue;

    if (EPI == 5 || EPI == 6 || EPI == 7) {
      const float2 st = statsIn[row];
      const float mu = st.x * (1.f / DM);
      const float rs = rsqrtf(st.y * (1.f / DM) - mu * mu + LNEPS);
      const float mrs = mu * rs;
#pragma unroll
      for (int j = 0; j < 4; ++j) {
        const int col = n0 + wc * 64 + j * 16 + lk * 4;
        float4 sp4 = *(const float4*)&sarr[col];
        float4 bb4 = *(const float4*)&barr[col];
        float v[4];
        v[0] = rs * acc[i][j][0] - mrs * sp4.x + bb4.x;
        v[1] = rs * acc[i][j][1] - mrs * sp4.y + bb4.y;
        v[2] = rs * acc[i][j][2] - mrs * sp4.z + bb4.z;
        v[3] = rs * acc[i][j][3] - mrs * sp4.w + bb4.w;
        if (EPI == 5) {
          short4_t pk;
#pragma unroll
          for (int rr = 0; rr < 4; ++rr) pk[rr] = f2bf(v[rr]);
          *(short4_t*)((bf16*)C + (size_t)row * ldc + col) = pk;
        } else if (EPI == 6) {
          short4_t pk;
#pragma unroll
          for (int rr = 0; rr < 4; ++rr)
            pk[rr] = f2bf(v[rr] / (1.f + __expf(-1.702f * v[rr])));
          *(short4_t*)((bf16*)C + (size_t)row * ldc + col) = pk;
        } else {
          const size_t orow = (size_t)(row & 63) * SL + (row >> 6);
          float4 o4 = {v[0], v[1], v[2], v[3]};
          *(float4*)((float*)C + orow * ldc + col) = o4;
        }
      }
    } else {
      // EPI 8 / 9: residual update + row-stat emission
      float s1 = 0.f, s2 = 0.f;
#pragma unroll
      for (int j = 0; j < 4; ++j) {
        const int col = n0 + wc * 64 + j * 16 + lk * 4;
        const size_t off = (size_t)row * ldc + col;
        float4 b4 = *(const float4*)&bias[col];
        const float bv[4] = {b4.x, b4.y, b4.z, b4.w};
        short4_t xv = *(const short4_t*)((const bf16*)C + off);
        float4 h4;
        if (EPI == 9) h4 = *(const float4*)&hook[off];
        const float hk[4] = {h4.x, h4.y, h4.z, h4.w};
        short4_t pk;
#pragma unroll
        for (int rr = 0; rr < 4; ++rr) {
          float t = bf2f(xv[rr]) + acc[i][j][rr] + bv[rr];
          if (EPI == 9) t = wmg * hk[rr] + omg * t;
          s1 += t;
          s2 += t * t;
          pk[rr] = f2bf(t);
        }
        *(short4_t*)((bf16*)C + off) = pk;
      }
      s1 += __shfl_xor(s1, 16);
      s1 += __shfl_xor(s1, 32);
      s2 += __shfl_xor(s2, 16);
      s2 += __shfl_xor(s2, 32);
      if (lk == 0) {
        atomicAdd(&statsOut[row].x, s1);
        atomicAdd(&statsOut[row].y, s2);
      }
    }
  }
}

// ---------------- driver ----------------
extern "C" void kernel_launch(void* const* d_in, const int* in_sizes, int n_in,
                              void* d_out, int out_size, void* d_ws, size_t ws_size,
                              hipStream_t stream) {
  const float* hook = (const float*)d_in[0];
  const float* alpha = (const float*)d_in[1];
  const float* ipw = (const float*)d_in[2];
  const float* ipb = (const float*)d_in[3];
  const float* opw = (const float*)d_in[4];
  const float* opb = (const float*)d_in[5];
  const float* l1w = (const float*)d_in[6];
  const float* l1b = (const float*)d_in[7];
  const float* l2w = (const float*)d_in[8];
  const float* l2b = (const float*)d_in[9];
  const float* fcw = (const float*)d_in[10];
  const float* fcb = (const float*)d_in[11];
  const float* cpw = (const float*)d_in[12];
  const float* cpb = (const float*)d_in[13];
  const float* lpw = (const float*)d_in[14];
  const float* lpb = (const float*)d_in[15];
  const float* proj = (const float*)d_in[16];

  char* ws = (char*)d_ws;
  size_t off = 0;
  bf16* x = (bf16*)(ws + off); off += (size_t)MP * DM * 2;
  bf16* qkv = (bf16*)(ws + off);
  bf16* mbuf = (bf16*)qkv;  // reuse qkv region for MLP intermediate
  off += (size_t)MP * 1024 * 2;
  bf16* obuf = (bf16*)(ws + off); off += (size_t)MP * DRED * 2;
  bf16* wq = (bf16*)(ws + off); off += (size_t)KBLK * 768 * DM * 2;
  bf16* wo = (bf16*)(ws + off); off += (size_t)KBLK * DM * DRED * 2;
  bf16* wfc = (bf16*)(ws + off); off += (size_t)KBLK * DM * DM * 2;
  bf16* wcp = (bf16*)(ws + off); off += (size_t)KBLK * DM * DM * 2;
  bf16* wpj = (bf16*)(ws + off); off += (size_t)768 * DM * 2;
  float2* stats = (float2*)(ws + off); off += (size_t)13 * MR * sizeof(float2);
  float* sq_q = (float*)(ws + off); off += (size_t)KBLK * 768 * 4;
  float* bb_q = (float*)(ws + off); off += (size_t)KBLK * 768 * 4;
  float* sq_fc = (float*)(ws + off); off += (size_t)KBLK * DM * 4;
  float* bb_fc = (float*)(ws + off); off += (size_t)KBLK * DM * 4;
  float* sq_pj = (float*)(ws + off); off += (size_t)768 * 4;
  float* bb_pj = (float*)(ws + off); off += (size_t)768 * 4;

  hipMemsetAsync(stats, 0, (size_t)13 * MR * sizeof(float2), stream);
  cast_all_kernel<<<9600, 256, 0, stream>>>(
      ipw, opw, fcw, cpw, proj, l1w, l1b, l2w, l2b, lpw, lpb, ipb, fcb,
      wq, wo, wfc, wcp, wpj, sq_q, bb_q, sq_fc, bb_fc, sq_pj, bb_pj);
  stat0_kernel<<<MR, 256, 0, stream>>>(hook, x, stats + (size_t)12 * MR);

  const dim3 gq(129, 6);   // N=768 grids: 774 wgs
  const dim3 gm(129, 8);   // N=1024 grids: 1032 wgs

  for (int i = 0; i < KBLK; ++i) {
    const float2* stIn = (i == 0) ? stats + (size_t)12 * MR
                                  : stats + (size_t)(2 * i - 1) * MR;
    // qkv = LN1(x) @ ipw^T + ipb   (fused LN via folded weights)
    gemm_kernel<5, 1024, 6><<<gq, 256, 0, stream>>>(
        x, DM, wq + (size_t)i * 768 * DM, DM, nullptr, qkv, 768,
        nullptr, nullptr, 0, stIn, sq_q + i * 768, bb_q + i * 768, nullptr);
    attn_mfma_kernel<<<BA * NHEAD, 256, 0, stream>>>(qkv, obuf);
    // x += attn_out @ opw^T + opb ; emit LN2 stats
    gemm_kernel<8, 256, 8><<<gm, 256, 0, stream>>>(
        obuf, DRED, wo + (size_t)i * DM * DRED, DRED, opb + i * DM, x, DM,
        nullptr, nullptr, 0, nullptr, nullptr, nullptr,
        stats + (size_t)(2 * i) * MR);
    // mbuf = quickgelu(LN2(x) @ fcw^T + fcb)  (fused LN)
    gemm_kernel<6, 1024, 8><<<gm, 256, 0, stream>>>(
        x, DM, wfc + (size_t)i * DM * DM, DM, nullptr, mbuf, DM,
        nullptr, nullptr, 0, stats + (size_t)(2 * i) * MR,
        sq_fc + i * DM, bb_fc + i * DM, nullptr);
    // x = [gate_{i+1}] (x + mbuf @ cpw^T + cpb) ; emit LN1(i+1)/LNpost stats
    if (i + 1 < KBLK)
      gemm_kernel<9, 1024, 8><<<gm, 256, 0, stream>>>(
          mbuf, DM, wcp + (size_t)i * DM * DM, DM, cpb + i * DM, x, DM,
          hook + (size_t)(i + 1) * MR * DM, alpha, i + 1,
          nullptr, nullptr, nullptr, stats + (size_t)(2 * i + 1) * MR);
    else
      gemm_kernel<8, 1024, 8><<<gm, 256, 0, stream>>>(
          mbuf, DM, wcp + (size_t)i * DM * DM, DM, cpb + i * DM, x, DM,
          nullptr, nullptr, 0, nullptr, nullptr, nullptr,
          stats + (size_t)(2 * i + 1) * MR);
  }
  // final: out[b*SL+s] = LN_post(x) @ proj  (fused LN, transposed write, fp32)
  gemm_kernel<7, 1024, 6><<<gq, 256, 0, stream>>>(
      x, DM, wpj, DM, nullptr, (float*)d_out, 768,
      nullptr, nullptr, 0, stats + (size_t)11 * MR, sq_pj, bb_pj, nullptr);
}

// Round 12
// 1526.172 us; speedup vs baseline: 3.3706x; 1.0529x over previous
//
#include <hip/hip_runtime.h>
#include <hip/hip_bf16.h>
#include <cstdint>
#include <cstddef>

// Problem constants
#define KBLK 6
#define SL 257
#define BA 64
#define DM 1024
#define NHEAD 16
#define DRED 256
#define HDM 16
#define MR (SL * BA)     // 16448 real rows
#define MP 16512         // 129 * 128 padded rows
#define LNEPS 1e-5f

typedef __hip_bfloat16 bf16;
typedef __attribute__((ext_vector_type(8))) short short8;
typedef __attribute__((ext_vector_type(4))) short short4_t;
typedef __attribute__((ext_vector_type(4))) float f32x4;

__device__ __forceinline__ void gld_lds16(const void* g, void* l) {
  __builtin_amdgcn_global_load_lds(
      (const __attribute__((address_space(1))) unsigned int*)g,
      (__attribute__((address_space(3))) unsigned int*)l, 16, 0, 0);
}

__device__ __forceinline__ float bf2f(short s) {
  bf16 t = *reinterpret_cast<bf16*>(&s);
  return __bfloat162float(t);
}
__device__ __forceinline__ short f2bf(float f) {
  bf16 t = __float2bfloat16(f);
  return *reinterpret_cast<short*>(&t);
}

// ---------------- fused: weight casts + LN folding + stat0 + stats zeroing ----------------
// blocks [0,9600): weight processing (as round 11)
// blocks [9600, 9600+MR): row r = blk-9600 of hook -> x (bf16), stats12[r] = (Σ,Σ²),
//                         zero stats[j*MR + r] for j=0..11 (atomic targets)
__global__ __launch_bounds__(256) void cast_all_kernel(
    const float* __restrict__ ipw, const float* __restrict__ opw,
    const float* __restrict__ fcw, const float* __restrict__ cpw,
    const float* __restrict__ proj,
    const float* __restrict__ l1w, const float* __restrict__ l1b,
    const float* __restrict__ l2w, const float* __restrict__ l2b,
    const float* __restrict__ lpw, const float* __restrict__ lpb,
    const float* __restrict__ ipb, const float* __restrict__ fcb,
    const float* __restrict__ hook, bf16* __restrict__ x,
    bf16* __restrict__ wq, bf16* __restrict__ wo, bf16* __restrict__ wfc,
    bf16* __restrict__ wcp, bf16* __restrict__ wpj,
    float* __restrict__ sq_q, float* __restrict__ bb_q,
    float* __restrict__ sq_fc, float* __restrict__ bb_fc,
    float* __restrict__ sq_pj, float* __restrict__ bb_pj,
    float2* __restrict__ stats) {
  const int blk = blockIdx.x;
  const int tid = threadIdx.x;

  if (blk >= 9600) {  // stat0 + zero
    const int row = blk - 9600;
    const size_t base = (size_t)row * DM + tid * 4;
    float4 v = *(const float4*)(hook + base);
    short4_t pk;
    pk[0] = f2bf(v.x); pk[1] = f2bf(v.y); pk[2] = f2bf(v.z); pk[3] = f2bf(v.w);
    *(short4_t*)&x[base] = pk;
    if (tid < 12) stats[(size_t)tid * MR + row] = make_float2(0.f, 0.f);
    float s1 = v.x + v.y + v.z + v.w;
    float s2 = v.x * v.x + v.y * v.y + v.z * v.z + v.w * v.w;
#pragma unroll
    for (int o = 32; o >= 1; o >>= 1) {
      s1 += __shfl_down(s1, o);
      s2 += __shfl_down(s2, o);
    }
    __shared__ float red[8];
    if ((tid & 63) == 0) {
      red[tid >> 6] = s1;
      red[4 + (tid >> 6)] = s2;
    }
    __syncthreads();
    if (tid == 0) {
      float t1 = red[0] + red[1] + red[2] + red[3];
      float t2 = red[4] + red[5] + red[6] + red[7];
      stats[(size_t)12 * MR + row] = make_float2(t1, t2);
    }
    return;
  }

  float sp = 0.f, bbp = 0.f;
  float* sqDst = nullptr;
  float* bbDst = nullptr;
  const float* bflat = nullptr;
  int grow = 0;

  if (blk < 2304) {  // wq: folded with l1
    const int base = blk * 2048, idx = base + tid * 8;
    grow = base >> 10;
    const int rowt = idx >> 10, col = idx & 1023;
    const int tb = rowt / 768;
    const float* lw = l1w + tb * DM;
    const float* lb = l1b + tb * DM;
    float4 a = *(const float4*)(ipw + idx);
    float4 b = *(const float4*)(ipw + idx + 4);
    float v[8] = {a.x, a.y, a.z, a.w, b.x, b.y, b.z, b.w};
    short8 o;
#pragma unroll
    for (int e = 0; e < 8; ++e) {
      float f = v[e] * lw[col + e];
      sp += f;
      bbp += lb[col + e] * v[e];
      o[e] = f2bf(f);
    }
    *(short8*)(wq + idx) = o;
    sqDst = sq_q; bbDst = bb_q; bflat = ipb;
  } else if (blk < 3072) {  // wo plain
    const int base = (blk - 2304) * 2048, idx = base + tid * 8;
    float4 a = *(const float4*)(opw + idx);
    float4 b = *(const float4*)(opw + idx + 4);
    short8 o;
    o[0] = f2bf(a.x); o[1] = f2bf(a.y); o[2] = f2bf(a.z); o[3] = f2bf(a.w);
    o[4] = f2bf(b.x); o[5] = f2bf(b.y); o[6] = f2bf(b.z); o[7] = f2bf(b.w);
    *(short8*)(wo + idx) = o;
  } else if (blk < 6144) {  // wfc: folded with l2
    const int base = (blk - 3072) * 2048, idx = base + tid * 8;
    grow = base >> 10;
    const int rowt = idx >> 10, col = idx & 1023;
    const int tb = rowt >> 10;
    const float* lw = l2w + tb * DM;
    const float* lb = l2b + tb * DM;
    float4 a = *(const float4*)(fcw + idx);
    float4 b = *(const float4*)(fcw + idx + 4);
    float v[8] = {a.x, a.y, a.z, a.w, b.x, b.y, b.z, b.w};
    short8 o;
#pragma unroll
    for (int e = 0; e < 8; ++e) {
      float f = v[e] * lw[col + e];
      sp += f;
      bbp += lb[col + e] * v[e];
      o[e] = f2bf(f);
    }
    *(short8*)(wfc + idx) = o;
    sqDst = sq_fc; bbDst = bb_fc; bflat = fcb;
  } else if (blk < 9216) {  // wcp plain
    const int base = (blk - 6144) * 2048, idx = base + tid * 8;
    float4 a = *(const float4*)(cpw + idx);
    float4 b = *(const float4*)(cpw + idx + 4);
    short8 o;
    o[0] = f2bf(a.x); o[1] = f2bf(a.y); o[2] = f2bf(a.z); o[3] = f2bf(a.w);
    o[4] = f2bf(b.x); o[5] = f2bf(b.y); o[6] = f2bf(b.z); o[7] = f2bf(b.w);
    *(short8*)(wcp + idx) = o;
  } else {  // wpj: transposed gather, folded with lnpost
    const int base = (blk - 9216) * 2048, idx = base + tid * 8;
    grow = base >> 10;
    const int n = idx >> 10, k0 = idx & 1023;
    short8 o;
#pragma unroll
    for (int e = 0; e < 8; ++e) {
      float v = proj[(size_t)(k0 + e) * 768 + n];
      float f = v * lpw[k0 + e];
      sp += f;
      bbp += lpb[k0 + e] * v;
      o[e] = f2bf(f);
    }
    *(short8*)(wpj + idx) = o;
    sqDst = sq_pj; bbDst = bb_pj; bflat = nullptr;
  }

  if (sqDst) {
#pragma unroll
    for (int o = 32; o >= 1; o >>= 1) {
      sp += __shfl_down(sp, o);
      bbp += __shfl_down(bbp, o);
    }
    __shared__ float wred[4][2];
    const int wave = tid >> 6;
    if ((tid & 63) == 0) {
      wred[wave][0] = sp;
      wred[wave][1] = bbp;
    }
    __syncthreads();
    if (tid == 0) {
      sqDst[grow] = wred[0][0] + wred[1][0];
      bbDst[grow] = wred[0][1] + wred[1][1] + (bflat ? bflat[grow] : 0.f);
    } else if (tid == 128) {
      sqDst[grow + 1] = wred[2][0] + wred[3][0];
      bbDst[grow + 1] = wred[2][1] + wred[3][1] + (bflat ? bflat[grow + 1] : 0.f);
    }
  }
}

// ---------------- MFMA attention (direct-Q variant, validated in round 8) ----------------
__global__ __launch_bounds__(256) void attn_mfma_kernel(const bf16* __restrict__ qkv,
                                                        bf16* __restrict__ obuf) {
  __shared__ __align__(16) short kl[272][24];
  __shared__ __align__(16) short vt[16][296];
  __shared__ __align__(16) short pl[4][16][40];
  const int bh = blockIdx.x;
  const int b = bh >> 4, h = bh & 15;
  const int tid = threadIdx.x;
  const int wave = tid >> 6, lane = tid & 63;
  const int g = lane >> 4, qi = lane & 15;

  const short8 zero8 = {0, 0, 0, 0, 0, 0, 0, 0};
  const f32x4 fzero = {0.f, 0.f, 0.f, 0.f};

  // stage K and V^T only (Q read direct from L2-hot qkv)
  for (int task = tid; task < 1088; task += 256) {
    int a = (task < 544) ? 1 : 2;
    int rem = (task < 544) ? task : task - 544;
    int row = rem >> 1, half = rem & 1;
    short8 v = zero8;
    if (row < SL)
      v = *(const short8*)((const short*)qkv + (size_t)(row * BA + b) * 768 + a * 256 + h * 16 + half * 8);
    if (a == 1) *(short8*)&kl[row][half * 8] = v;
    else {
#pragma unroll
      for (int j = 0; j < 8; ++j) vt[half * 8 + j][row] = v[j];
    }
  }
  for (int i = tid; i < 16 * 24; i += 256) vt[i / 24][272 + (i % 24)] = 0;
  __syncthreads();

  for (int t = wave; t < 17; t += 4) {
    const int qrow = t * 16 + qi;
    short8 bq = zero8;
    if (g < 2 && qrow < SL)
      bq = *(const short8*)((const short*)qkv + (size_t)(qrow * BA + b) * 768 + h * 16 + g * 8);

    f32x4 st[18];
#pragma unroll
    for (int t2 = 0; t2 < 17; ++t2) {
      short8 ak = zero8;
      if (g < 2) ak = *(const short8*)&kl[t2 * 16 + qi][g * 8];
      st[t2] = __builtin_amdgcn_mfma_f32_16x16x32_bf16(ak, bq, fzero, 0, 0, 0);
    }
    float mx = -1e30f;
#pragma unroll
    for (int t2 = 0; t2 < 17; ++t2) {
#pragma unroll
      for (int r = 0; r < 4; ++r) {
        int s = t2 * 16 + g * 4 + r;
        float v = (s <= 256) ? st[t2][r] * 0.25f : -1e30f;
        st[t2][r] = v;
        mx = fmaxf(mx, v);
      }
    }
    mx = fmaxf(mx, __shfl_xor(mx, 16));
    mx = fmaxf(mx, __shfl_xor(mx, 32));
    float ls = 0.f;
#pragma unroll
    for (int t2 = 0; t2 < 17; ++t2) {
#pragma unroll
      for (int r = 0; r < 4; ++r) {
        float p = __expf(st[t2][r] - mx);
        st[t2][r] = p;
        ls += p;
      }
    }
    ls += __shfl_xor(ls, 16);
    ls += __shfl_xor(ls, 32);
    const float inv = 1.f / ls;
#pragma unroll
    for (int t2 = 0; t2 < 17; ++t2)
#pragma unroll
      for (int r = 0; r < 4; ++r) st[t2][r] *= inv;
    st[17] = fzero;

    f32x4 acc = fzero;
#pragma unroll
    for (int tt = 0; tt < 9; ++tt) {
#pragma unroll
      for (int hh = 0; hh < 2; ++hh) {
        int t2 = tt * 2 + hh;
        short4_t pk;
#pragma unroll
        for (int r = 0; r < 4; ++r) pk[r] = f2bf(st[t2][r]);
        *(short4_t*)&pl[wave][qi][hh * 16 + g * 4] = pk;
      }
      short8 pa = *(const short8*)&pl[wave][qi][g * 8];
      short8 bv = *(const short8*)&vt[qi][tt * 32 + g * 8];
      acc = __builtin_amdgcn_mfma_f32_16x16x32_bf16(pa, bv, acc, 0, 0, 0);
    }
#pragma unroll
    for (int r = 0; r < 4; ++r) {
      int qr = t * 16 + g * 4 + r;
      if (qr < SL)
        obuf[(size_t)(qr * BA + b) * DRED + h * 16 + qi] = __float2bfloat16(acc[r]);
    }
  }
}

// ---------------- unified 128x128 GEMM (validated mainloop) ----------------
// EPI 5: bf16 out = rs*acc - mu*rs*S'[n] + BB[n]                (fused-LN consumer, qkv)
// EPI 6: bf16 quickgelu(same)                                   (fc)
// EPI 7: fp32 out at transposed row (LN_post consumer, final proj)
// EPI 8: bf16 RMW C += acc + bias; emit row stats               (op / cproj last)
// EPI 9: bf16 C = wm*hook + (1-wm)*(C + acc + bias); emit stats (cproj gated)
template <int EPI, int KDIM, int NT>
__global__ __launch_bounds__(256, 4) void gemm_kernel(
    const bf16* __restrict__ A, int lda,
    const bf16* __restrict__ Bw, int ldb,
    const float* __restrict__ bias,
    void* __restrict__ C, int ldc,
    const float* __restrict__ hook, const float* __restrict__ alphap, int kidx,
    const float2* __restrict__ statsIn,
    const float* __restrict__ sarr, const float* __restrict__ barr,
    float2* __restrict__ statsOut) {
  __shared__ char lds[32768];  // A 16KB | B 16KB, BK=64
  const int tid = threadIdx.x;
  const int wave = tid >> 6, lane = tid & 63;
  const int lrow = lane & 15, lk = lane >> 4;
  const int wr = wave >> 1, wc = wave & 1;

  constexpr int nwg = 129 * NT;
  constexpr int q = nwg >> 3, r = nwg & 7;
  const int orig = blockIdx.y * 129 + blockIdx.x;
  const int xcd = orig & 7, idx = orig >> 3;
  const int wgid = (xcd < r ? xcd * (q + 1) : r * (q + 1) + (xcd - r) * q) + idx;
  const int m0 = (wgid / NT) * 128;
  const int n0 = (wgid % NT) * 128;

  f32x4 acc[4][4];
  const f32x4 zero = {0.f, 0.f, 0.f, 0.f};
#pragma unroll
  for (int i = 0; i < 4; ++i)
#pragma unroll
    for (int j = 0; j < 4; ++j) acc[i][j] = zero;

  constexpr int nk = KDIM >> 6;

  for (int kt = 0; kt < nk; ++kt) {
    const int k0 = kt << 6;
#pragma unroll
    for (int j = 0; j < 4; ++j) {
      int c = wave * 256 + j * 64 + lane;
      int row = c >> 3, segp = c & 7;
      int seg = segp ^ (row & 7);
      gld_lds16(A + (size_t)(m0 + row) * lda + k0 + seg * 8, &lds[c * 16]);
      gld_lds16(Bw + (size_t)(n0 + row) * ldb + k0 + seg * 8, &lds[16384 + c * 16]);
    }
    __syncthreads();
#pragma unroll
    for (int kh = 0; kh < 2; ++kh) {
      short8 af[4], bfr[4];
#pragma unroll
      for (int i = 0; i < 4; ++i) {
        int rr = wr * 64 + i * 16 + lrow;
        int seg = kh * 4 + lk;
        af[i] = *(const short8*)(lds + rr * 128 + ((seg ^ (rr & 7)) << 4));
      }
#pragma unroll
      for (int j = 0; j < 4; ++j) {
        int rr = wc * 64 + j * 16 + lrow;
        int seg = kh * 4 + lk;
        bfr[j] = *(const short8*)(lds + 16384 + rr * 128 + ((seg ^ (rr & 7)) << 4));
      }
      // swapped operands: lane's 4 acc elems are column-consecutive
#pragma unroll
      for (int i = 0; i < 4; ++i)
#pragma unroll
        for (int j = 0; j < 4; ++j)
          acc[i][j] = __builtin_amdgcn_mfma_f32_16x16x32_bf16(bfr[j], af[i], acc[i][j], 0, 0, 0);
    }
    __syncthreads();
  }

  float wmg = 0.f, omg = 0.f;
  if (EPI == 9) {
    wmg = 1.f / (1.f + __expf(-alphap[kidx] * 10.f));
    omg = 1.f - wmg;
  }

  // column-indexed constants hoisted out of the i-loop
  float4 cj0[4], cj1[4];
#pragma unroll
  for (int j = 0; j < 4; ++j) {
    const int col = n0 + wc * 64 + j * 16 + lk * 4;
    if (EPI == 5 || EPI == 6 || EPI == 7) {
      cj0[j] = *(const float4*)&sarr[col];
      cj1[j] = *(const float4*)&barr[col];
    } else {
      cj0[j] = *(const float4*)&bias[col];
    }
  }

#pragma unroll
  for (int i = 0; i < 4; ++i) {
    const int row = m0 + wr * 64 + i * 16 + lrow;
    if (row >= MR) continue;

    if (EPI == 5 || EPI == 6 || EPI == 7) {
      const float2 st = statsIn[row];
      const float mu = st.x * (1.f / DM);
      const float rs = rsqrtf(st.y * (1.f / DM) - mu * mu + LNEPS);
      const float mrs = mu * rs;
#pragma unroll
      for (int j = 0; j < 4; ++j) {
        const int col = n0 + wc * 64 + j * 16 + lk * 4;
        float v[4];
        v[0] = rs * acc[i][j][0] - mrs * cj0[j].x + cj1[j].x;
        v[1] = rs * acc[i][j][1] - mrs * cj0[j].y + cj1[j].y;
        v[2] = rs * acc[i][j][2] - mrs * cj0[j].z + cj1[j].z;
        v[3] = rs * acc[i][j][3] - mrs * cj0[j].w + cj1[j].w;
        if (EPI == 5) {
          short4_t pk;
#pragma unroll
          for (int rr = 0; rr < 4; ++rr) pk[rr] = f2bf(v[rr]);
          *(short4_t*)((bf16*)C + (size_t)row * ldc + col) = pk;
        } else if (EPI == 6) {
          short4_t pk;
#pragma unroll
          for (int rr = 0; rr < 4; ++rr)
            pk[rr] = f2bf(v[rr] / (1.f + __expf(-1.702f * v[rr])));
          *(short4_t*)((bf16*)C + (size_t)row * ldc + col) = pk;
        } else {
          const size_t orow = (size_t)(row & 63) * SL + (row >> 6);
          float4 o4 = {v[0], v[1], v[2], v[3]};
          *(float4*)((float*)C + orow * ldc + col) = o4;
        }
      }
    } else {
      // EPI 8 / 9: residual update + row-stat emission
      float s1 = 0.f, s2 = 0.f;
#pragma unroll
      for (int j = 0; j < 4; ++j) {
        const int col = n0 + wc * 64 + j * 16 + lk * 4;
        const size_t off = (size_t)row * ldc + col;
        const float bv[4] = {cj0[j].x, cj0[j].y, cj0[j].z, cj0[j].w};
        short4_t xv = *(const short4_t*)((const bf16*)C + off);
        float4 h4;
        if (EPI == 9) h4 = *(const float4*)&hook[off];
        const float hk[4] = {h4.x, h4.y, h4.z, h4.w};
        short4_t pk;
#pragma unroll
        for (int rr = 0; rr < 4; ++rr) {
          float t = bf2f(xv[rr]) + acc[i][j][rr] + bv[rr];
          if (EPI == 9) t = wmg * hk[rr] + omg * t;
          s1 += t;
          s2 += t * t;
          pk[rr] = f2bf(t);
        }
        *(short4_t*)((bf16*)C + off) = pk;
      }
      s1 += __shfl_xor(s1, 16);
      s1 += __shfl_xor(s1, 32);
      s2 += __shfl_xor(s2, 16);
      s2 += __shfl_xor(s2, 32);
      if (lk == 0) {
        atomicAdd(&statsOut[row].x, s1);
        atomicAdd(&statsOut[row].y, s2);
      }
    }
  }
}

// ---------------- driver ----------------
extern "C" void kernel_launch(void* const* d_in, const int* in_sizes, int n_in,
                              void* d_out, int out_size, void* d_ws, size_t ws_size,
                              hipStream_t stream) {
  const float* hook = (const float*)d_in[0];
  const float* alpha = (const float*)d_in[1];
  const float* ipw = (const float*)d_in[2];
  const float* ipb = (const float*)d_in[3];
  const float* opw = (const float*)d_in[4];
  const float* opb = (const float*)d_in[5];
  const float* l1w = (const float*)d_in[6];
  const float* l1b = (const float*)d_in[7];
  const float* l2w = (const float*)d_in[8];
  const float* l2b = (const float*)d_in[9];
  const float* fcw = (const float*)d_in[10];
  const float* fcb = (const float*)d_in[11];
  const float* cpw = (const float*)d_in[12];
  const float* cpb = (const float*)d_in[13];
  const float* lpw = (const float*)d_in[14];
  const float* lpb = (const float*)d_in[15];
  const float* proj = (const float*)d_in[16];

  char* ws = (char*)d_ws;
  size_t off = 0;
  bf16* x = (bf16*)(ws + off); off += (size_t)MP * DM * 2;
  bf16* qkv = (bf16*)(ws + off);
  bf16* mbuf = (bf16*)qkv;  // reuse qkv region for MLP intermediate
  off += (size_t)MP * 1024 * 2;
  bf16* obuf = (bf16*)(ws + off); off += (size_t)MP * DRED * 2;
  bf16* wq = (bf16*)(ws + off); off += (size_t)KBLK * 768 * DM * 2;
  bf16* wo = (bf16*)(ws + off); off += (size_t)KBLK * DM * DRED * 2;
  bf16* wfc = (bf16*)(ws + off); off += (size_t)KBLK * DM * DM * 2;
  bf16* wcp = (bf16*)(ws + off); off += (size_t)KBLK * DM * DM * 2;
  bf16* wpj = (bf16*)(ws + off); off += (size_t)768 * DM * 2;
  float2* stats = (float2*)(ws + off); off += (size_t)13 * MR * sizeof(float2);
  float* sq_q = (float*)(ws + off); off += (size_t)KBLK * 768 * 4;
  float* bb_q = (float*)(ws + off); off += (size_t)KBLK * 768 * 4;
  float* sq_fc = (float*)(ws + off); off += (size_t)KBLK * DM * 4;
  float* bb_fc = (float*)(ws + off); off += (size_t)KBLK * DM * 4;
  float* sq_pj = (float*)(ws + off); off += (size_t)768 * 4;
  float* bb_pj = (float*)(ws + off); off += (size_t)768 * 4;

  cast_all_kernel<<<9600 + MR, 256, 0, stream>>>(
      ipw, opw, fcw, cpw, proj, l1w, l1b, l2w, l2b, lpw, lpb, ipb, fcb,
      hook, x,
      wq, wo, wfc, wcp, wpj, sq_q, bb_q, sq_fc, bb_fc, sq_pj, bb_pj, stats);

  const dim3 gq(129, 6);   // N=768 grids: 774 wgs
  const dim3 gm(129, 8);   // N=1024 grids: 1032 wgs

  for (int i = 0; i < KBLK; ++i) {
    const float2* stIn = (i == 0) ? stats + (size_t)12 * MR
                                  : stats + (size_t)(2 * i - 1) * MR;
    // qkv = LN1(x) @ ipw^T + ipb   (fused LN via folded weights)
    gemm_kernel<5, 1024, 6><<<gq, 256, 0, stream>>>(
        x, DM, wq + (size_t)i * 768 * DM, DM, nullptr, qkv, 768,
        nullptr, nullptr, 0, stIn, sq_q + i * 768, bb_q + i * 768, nullptr);
    attn_mfma_kernel<<<BA * NHEAD, 256, 0, stream>>>(qkv, obuf);
    // x += attn_out @ opw^T + opb ; emit LN2 stats
    gemm_kernel<8, 256, 8><<<gm, 256, 0, stream>>>(
        obuf, DRED, wo + (size_t)i * DM * DRED, DRED, opb + i * DM, x, DM,
        nullptr, nullptr, 0, nullptr, nullptr, nullptr,
        stats + (size_t)(2 * i) * MR);
    // mbuf = quickgelu(LN2(x) @ fcw^T + fcb)  (fused LN)
    gemm_kernel<6, 1024, 8><<<gm, 256, 0, stream>>>(
        x, DM, wfc + (size_t)i * DM * DM, DM, nullptr, mbuf, DM,
        nullptr, nullptr, 0, stats + (size_t)(2 * i) * MR,
        sq_fc + i * DM, bb_fc + i * DM, nullptr);
    // x = [gate_{i+1}] (x + mbuf @ cpw^T + cpb) ; emit LN1(i+1)/LNpost stats
    if (i + 1 < KBLK)
      gemm_kernel<9, 1024, 8><<<gm, 256, 0, stream>>>(
          mbuf, DM, wcp + (size_t)i * DM * DM, DM, cpb + i * DM, x, DM,
          hook + (size_t)(i + 1) * MR * DM, alpha, i + 1,
          nullptr, nullptr, nullptr, stats + (size_t)(2 * i + 1) * MR);
    else
      gemm_kernel<8, 1024, 8><<<gm, 256, 0, stream>>>(
          mbuf, DM, wcp + (size_t)i * DM * DM, DM, cpb + i * DM, x, DM,
          nullptr, nullptr, 0, nullptr, nullptr, nullptr,
          stats + (size_t)(2 * i + 1) * MR);
  }
  // final: out[b*SL+s] = LN_post(x) @ proj  (fused LN, transposed write, fp32)
  gemm_kernel<7, 1024, 6><<<gq, 256, 0, stream>>>(
      x, DM, wpj, DM, nullptr, (float*)d_out, 768,
      nullptr, nullptr, 0, stats + (size_t)11 * MR, sq_pj, bb_pj, nullptr);
}

// Round 13
// 1502.350 us; speedup vs baseline: 3.4240x; 1.0159x over previous
//
#include <hip/hip_runtime.h>
#include <hip/hip_bf16.h>
#include <cstdint>
#include <cstddef>

// Problem constants
#define KBLK 6
#define SL 257
#define BA 64
#define DM 1024
#define NHEAD 16
#define DRED 256
#define HDM 16
#define MR (SL * BA)     // 16448 real rows
#define MP 16512         // 129 * 128 padded rows
#define LNEPS 1e-5f

typedef __hip_bfloat16 bf16;
typedef __attribute__((ext_vector_type(8))) short short8;
typedef __attribute__((ext_vector_type(4))) short short4_t;
typedef __attribute__((ext_vector_type(4))) float f32x4;

__device__ __forceinline__ void gld_lds16(const void* g, void* l) {
  __builtin_amdgcn_global_load_lds(
      (const __attribute__((address_space(1))) unsigned int*)g,
      (__attribute__((address_space(3))) unsigned int*)l, 16, 0, 0);
}

__device__ __forceinline__ float bf2f(short s) {
  bf16 t = *reinterpret_cast<bf16*>(&s);
  return __bfloat162float(t);
}
__device__ __forceinline__ short f2bf(float f) {
  bf16 t = __float2bfloat16(f);
  return *reinterpret_cast<short*>(&t);
}

// ---------------- fused: weight casts + LN folding + stat0 + stats zeroing ----------------
// blocks [0,9600): weight processing
// blocks [9600, 9600+MR): row r = blk-9600 of hook -> x (bf16), stats12[r] = (Σ,Σ²),
//                         zero stats[j*MR + r] for j=0..11 (atomic targets)
__global__ __launch_bounds__(256) void cast_all_kernel(
    const float* __restrict__ ipw, const float* __restrict__ opw,
    const float* __restrict__ fcw, const float* __restrict__ cpw,
    const float* __restrict__ proj,
    const float* __restrict__ l1w, const float* __restrict__ l1b,
    const float* __restrict__ l2w, const float* __restrict__ l2b,
    const float* __restrict__ lpw, const float* __restrict__ lpb,
    const float* __restrict__ ipb, const float* __restrict__ fcb,
    const float* __restrict__ hook, bf16* __restrict__ x,
    bf16* __restrict__ wq, bf16* __restrict__ wo, bf16* __restrict__ wfc,
    bf16* __restrict__ wcp, bf16* __restrict__ wpj,
    float* __restrict__ sq_q, float* __restrict__ bb_q,
    float* __restrict__ sq_fc, float* __restrict__ bb_fc,
    float* __restrict__ sq_pj, float* __restrict__ bb_pj,
    float2* __restrict__ stats) {
  const int blk = blockIdx.x;
  const int tid = threadIdx.x;

  if (blk >= 9600) {  // stat0 + zero
    const int row = blk - 9600;
    const size_t base = (size_t)row * DM + tid * 4;
    float4 v = *(const float4*)(hook + base);
    short4_t pk;
    pk[0] = f2bf(v.x); pk[1] = f2bf(v.y); pk[2] = f2bf(v.z); pk[3] = f2bf(v.w);
    *(short4_t*)&x[base] = pk;
    if (tid < 12) stats[(size_t)tid * MR + row] = make_float2(0.f, 0.f);
    float s1 = v.x + v.y + v.z + v.w;
    float s2 = v.x * v.x + v.y * v.y + v.z * v.z + v.w * v.w;
#pragma unroll
    for (int o = 32; o >= 1; o >>= 1) {
      s1 += __shfl_down(s1, o);
      s2 += __shfl_down(s2, o);
    }
    __shared__ float red[8];
    if ((tid & 63) == 0) {
      red[tid >> 6] = s1;
      red[4 + (tid >> 6)] = s2;
    }
    __syncthreads();
    if (tid == 0) {
      float t1 = red[0] + red[1] + red[2] + red[3];
      float t2 = red[4] + red[5] + red[6] + red[7];
      stats[(size_t)12 * MR + row] = make_float2(t1, t2);
    }
    return;
  }

  float sp = 0.f, bbp = 0.f;
  float* sqDst = nullptr;
  float* bbDst = nullptr;
  const float* bflat = nullptr;
  int grow = 0;

  if (blk < 2304) {  // wq: folded with l1
    const int base = blk * 2048, idx = base + tid * 8;
    grow = base >> 10;
    const int rowt = idx >> 10, col = idx & 1023;
    const int tb = rowt / 768;
    const float* lw = l1w + tb * DM;
    const float* lb = l1b + tb * DM;
    float4 a = *(const float4*)(ipw + idx);
    float4 b = *(const float4*)(ipw + idx + 4);
    float v[8] = {a.x, a.y, a.z, a.w, b.x, b.y, b.z, b.w};
    short8 o;
#pragma unroll
    for (int e = 0; e < 8; ++e) {
      float f = v[e] * lw[col + e];
      sp += f;
      bbp += lb[col + e] * v[e];
      o[e] = f2bf(f);
    }
    *(short8*)(wq + idx) = o;
    sqDst = sq_q; bbDst = bb_q; bflat = ipb;
  } else if (blk < 3072) {  // wo plain
    const int base = (blk - 2304) * 2048, idx = base + tid * 8;
    float4 a = *(const float4*)(opw + idx);
    float4 b = *(const float4*)(opw + idx + 4);
    short8 o;
    o[0] = f2bf(a.x); o[1] = f2bf(a.y); o[2] = f2bf(a.z); o[3] = f2bf(a.w);
    o[4] = f2bf(b.x); o[5] = f2bf(b.y); o[6] = f2bf(b.z); o[7] = f2bf(b.w);
    *(short8*)(wo + idx) = o;
  } else if (blk < 6144) {  // wfc: folded with l2
    const int base = (blk - 3072) * 2048, idx = base + tid * 8;
    grow = base >> 10;
    const int rowt = idx >> 10, col = idx & 1023;
    const int tb = rowt >> 10;
    const float* lw = l2w + tb * DM;
    const float* lb = l2b + tb * DM;
    float4 a = *(const float4*)(fcw + idx);
    float4 b = *(const float4*)(fcw + idx + 4);
    float v[8] = {a.x, a.y, a.z, a.w, b.x, b.y, b.z, b.w};
    short8 o;
#pragma unroll
    for (int e = 0; e < 8; ++e) {
      float f = v[e] * lw[col + e];
      sp += f;
      bbp += lb[col + e] * v[e];
      o[e] = f2bf(f);
    }
    *(short8*)(wfc + idx) = o;
    sqDst = sq_fc; bbDst = bb_fc; bflat = fcb;
  } else if (blk < 9216) {  // wcp plain
    const int base = (blk - 6144) * 2048, idx = base + tid * 8;
    float4 a = *(const float4*)(cpw + idx);
    float4 b = *(const float4*)(cpw + idx + 4);
    short8 o;
    o[0] = f2bf(a.x); o[1] = f2bf(a.y); o[2] = f2bf(a.z); o[3] = f2bf(a.w);
    o[4] = f2bf(b.x); o[5] = f2bf(b.y); o[6] = f2bf(b.z); o[7] = f2bf(b.w);
    *(short8*)(wcp + idx) = o;
  } else {  // wpj: transposed gather, folded with lnpost
    const int base = (blk - 9216) * 2048, idx = base + tid * 8;
    grow = base >> 10;
    const int n = idx >> 10, k0 = idx & 1023;
    short8 o;
#pragma unroll
    for (int e = 0; e < 8; ++e) {
      float v = proj[(size_t)(k0 + e) * 768 + n];
      float f = v * lpw[k0 + e];
      sp += f;
      bbp += lpb[k0 + e] * v;
      o[e] = f2bf(f);
    }
    *(short8*)(wpj + idx) = o;
    sqDst = sq_pj; bbDst = bb_pj; bflat = nullptr;
  }

  if (sqDst) {
#pragma unroll
    for (int o = 32; o >= 1; o >>= 1) {
      sp += __shfl_down(sp, o);
      bbp += __shfl_down(bbp, o);
    }
    __shared__ float wred[4][2];
    const int wave = tid >> 6;
    if ((tid & 63) == 0) {
      wred[wave][0] = sp;
      wred[wave][1] = bbp;
    }
    __syncthreads();
    if (tid == 0) {
      sqDst[grow] = wred[0][0] + wred[1][0];
      bbDst[grow] = wred[0][1] + wred[1][1] + (bflat ? bflat[grow] : 0.f);
    } else if (tid == 128) {
      sqDst[grow + 1] = wred[2][0] + wred[3][0];
      bbDst[grow + 1] = wred[2][1] + wred[3][1] + (bflat ? bflat[grow + 1] : 0.f);
    }
  }
}

// ---------------- MFMA attention (direct-Q, XCD-swizzled bh) ----------------
// bh swizzle: hardware block B runs on XCD B%8; map logical bh = (B&7)*128 + (B>>3)
// so each XCD owns a CONTIGUOUS 128-bh range = 8 full b values x 16 heads ->
// qkv cachelines (shared by 4 adjacent heads) stay within one XCD's L2,
// and each XCD's qkv slice (~3.1 MB) is L2-resident.
__global__ __launch_bounds__(256) void attn_mfma_kernel(const bf16* __restrict__ qkv,
                                                        bf16* __restrict__ obuf) {
  __shared__ __align__(16) short kl[272][24];
  __shared__ __align__(16) short vt[16][296];
  __shared__ __align__(16) short pl[4][16][40];
  const int orig = blockIdx.x;
  const int bh = (orig & 7) * 128 + (orig >> 3);  // bijective: 1024 % 8 == 0
  const int b = bh >> 4, h = bh & 15;
  const int tid = threadIdx.x;
  const int wave = tid >> 6, lane = tid & 63;
  const int g = lane >> 4, qi = lane & 15;

  const short8 zero8 = {0, 0, 0, 0, 0, 0, 0, 0};
  const f32x4 fzero = {0.f, 0.f, 0.f, 0.f};

  // stage K and V^T only (Q read direct from L2-hot qkv)
  for (int task = tid; task < 1088; task += 256) {
    int a = (task < 544) ? 1 : 2;
    int rem = (task < 544) ? task : task - 544;
    int row = rem >> 1, half = rem & 1;
    short8 v = zero8;
    if (row < SL)
      v = *(const short8*)((const short*)qkv + (size_t)(row * BA + b) * 768 + a * 256 + h * 16 + half * 8);
    if (a == 1) *(short8*)&kl[row][half * 8] = v;
    else {
#pragma unroll
      for (int j = 0; j < 8; ++j) vt[half * 8 + j][row] = v[j];
    }
  }
  for (int i = tid; i < 16 * 24; i += 256) vt[i / 24][272 + (i % 24)] = 0;
  __syncthreads();

  for (int t = wave; t < 17; t += 4) {
    const int qrow = t * 16 + qi;
    short8 bq = zero8;
    if (g < 2 && qrow < SL)
      bq = *(const short8*)((const short*)qkv + (size_t)(qrow * BA + b) * 768 + h * 16 + g * 8);

    f32x4 st[18];
#pragma unroll
    for (int t2 = 0; t2 < 17; ++t2) {
      short8 ak = zero8;
      if (g < 2) ak = *(const short8*)&kl[t2 * 16 + qi][g * 8];
      st[t2] = __builtin_amdgcn_mfma_f32_16x16x32_bf16(ak, bq, fzero, 0, 0, 0);
    }
    float mx = -1e30f;
#pragma unroll
    for (int t2 = 0; t2 < 17; ++t2) {
#pragma unroll
      for (int r = 0; r < 4; ++r) {
        int s = t2 * 16 + g * 4 + r;
        float v = (s <= 256) ? st[t2][r] * 0.25f : -1e30f;
        st[t2][r] = v;
        mx = fmaxf(mx, v);
      }
    }
    mx = fmaxf(mx, __shfl_xor(mx, 16));
    mx = fmaxf(mx, __shfl_xor(mx, 32));
    float ls = 0.f;
#pragma unroll
    for (int t2 = 0; t2 < 17; ++t2) {
#pragma unroll
      for (int r = 0; r < 4; ++r) {
        float p = __expf(st[t2][r] - mx);
        st[t2][r] = p;
        ls += p;
      }
    }
    ls += __shfl_xor(ls, 16);
    ls += __shfl_xor(ls, 32);
    const float inv = 1.f / ls;
#pragma unroll
    for (int t2 = 0; t2 < 17; ++t2)
#pragma unroll
      for (int r = 0; r < 4; ++r) st[t2][r] *= inv;
    st[17] = fzero;

    f32x4 acc = fzero;
#pragma unroll
    for (int tt = 0; tt < 9; ++tt) {
#pragma unroll
      for (int hh = 0; hh < 2; ++hh) {
        int t2 = tt * 2 + hh;
        short4_t pk;
#pragma unroll
        for (int r = 0; r < 4; ++r) pk[r] = f2bf(st[t2][r]);
        *(short4_t*)&pl[wave][qi][hh * 16 + g * 4] = pk;
      }
      short8 pa = *(const short8*)&pl[wave][qi][g * 8];
      short8 bv = *(const short8*)&vt[qi][tt * 32 + g * 8];
      acc = __builtin_amdgcn_mfma_f32_16x16x32_bf16(pa, bv, acc, 0, 0, 0);
    }
#pragma unroll
    for (int r = 0; r < 4; ++r) {
      int qr = t * 16 + g * 4 + r;
      if (qr < SL)
        obuf[(size_t)(qr * BA + b) * DRED + h * 16 + qi] = __float2bfloat16(acc[r]);
    }
  }
}

// ---------------- unified 128x128 GEMM (validated mainloop) ----------------
// EPI 5: bf16 out = rs*acc - mu*rs*S'[n] + BB[n]                (fused-LN consumer, qkv)
// EPI 6: bf16 quickgelu(same)                                   (fc)
// EPI 7: fp32 out at transposed row (LN_post consumer, final proj)
// EPI 8: bf16 RMW C += acc + bias; emit row stats               (op / cproj last)
// EPI 9: bf16 C = wm*hook + (1-wm)*(C + acc + bias); emit stats (cproj gated)
template <int EPI, int KDIM, int NT>
__global__ __launch_bounds__(256, 4) void gemm_kernel(
    const bf16* __restrict__ A, int lda,
    const bf16* __restrict__ Bw, int ldb,
    const float* __restrict__ bias,
    void* __restrict__ C, int ldc,
    const float* __restrict__ hook, const float* __restrict__ alphap, int kidx,
    const float2* __restrict__ statsIn,
    const float* __restrict__ sarr, const float* __restrict__ barr,
    float2* __restrict__ statsOut) {
  __shared__ char lds[32768];  // A 16KB | B 16KB, BK=64
  const int tid = threadIdx.x;
  const int wave = tid >> 6, lane = tid & 63;
  const int lrow = lane & 15, lk = lane >> 4;
  const int wr = wave >> 1, wc = wave & 1;

  constexpr int nwg = 129 * NT;
  constexpr int q = nwg >> 3, r = nwg & 7;
  const int orig = blockIdx.y * 129 + blockIdx.x;
  const int xcd = orig & 7, idx = orig >> 3;
  const int wgid = (xcd < r ? xcd * (q + 1) : r * (q + 1) + (xcd - r) * q) + idx;
  const int m0 = (wgid / NT) * 128;
  const int n0 = (wgid % NT) * 128;

  f32x4 acc[4][4];
  const f32x4 zero = {0.f, 0.f, 0.f, 0.f};
#pragma unroll
  for (int i = 0; i < 4; ++i)
#pragma unroll
    for (int j = 0; j < 4; ++j) acc[i][j] = zero;

  constexpr int nk = KDIM >> 6;

  for (int kt = 0; kt < nk; ++kt) {
    const int k0 = kt << 6;
#pragma unroll
    for (int j = 0; j < 4; ++j) {
      int c = wave * 256 + j * 64 + lane;
      int row = c >> 3, segp = c & 7;
      int seg = segp ^ (row & 7);
      gld_lds16(A + (size_t)(m0 + row) * lda + k0 + seg * 8, &lds[c * 16]);
      gld_lds16(Bw + (size_t)(n0 + row) * ldb + k0 + seg * 8, &lds[16384 + c * 16]);
    }
    __syncthreads();
#pragma unroll
    for (int kh = 0; kh < 2; ++kh) {
      short8 af[4], bfr[4];
#pragma unroll
      for (int i = 0; i < 4; ++i) {
        int rr = wr * 64 + i * 16 + lrow;
        int seg = kh * 4 + lk;
        af[i] = *(const short8*)(lds + rr * 128 + ((seg ^ (rr & 7)) << 4));
      }
#pragma unroll
      for (int j = 0; j < 4; ++j) {
        int rr = wc * 64 + j * 16 + lrow;
        int seg = kh * 4 + lk;
        bfr[j] = *(const short8*)(lds + 16384 + rr * 128 + ((seg ^ (rr & 7)) << 4));
      }
      // swapped operands: lane's 4 acc elems are column-consecutive
#pragma unroll
      for (int i = 0; i < 4; ++i)
#pragma unroll
        for (int j = 0; j < 4; ++j)
          acc[i][j] = __builtin_amdgcn_mfma_f32_16x16x32_bf16(bfr[j], af[i], acc[i][j], 0, 0, 0);
    }
    __syncthreads();
  }

  float wmg = 0.f, omg = 0.f;
  if (EPI == 9) {
    wmg = 1.f / (1.f + __expf(-alphap[kidx] * 10.f));
    omg = 1.f - wmg;
  }

  // column-indexed constants hoisted out of the i-loop
  float4 cj0[4], cj1[4];
#pragma unroll
  for (int j = 0; j < 4; ++j) {
    const int col = n0 + wc * 64 + j * 16 + lk * 4;
    if (EPI == 5 || EPI == 6 || EPI == 7) {
      cj0[j] = *(const float4*)&sarr[col];
      cj1[j] = *(const float4*)&barr[col];
    } else {
      cj0[j] = *(const float4*)&bias[col];
    }
  }

#pragma unroll
  for (int i = 0; i < 4; ++i) {
    const int row = m0 + wr * 64 + i * 16 + lrow;
    if (row >= MR) continue;

    if (EPI == 5 || EPI == 6 || EPI == 7) {
      const float2 st = statsIn[row];
      const float mu = st.x * (1.f / DM);
      const float rs = rsqrtf(st.y * (1.f / DM) - mu * mu + LNEPS);
      const float mrs = mu * rs;
#pragma unroll
      for (int j = 0; j < 4; ++j) {
        const int col = n0 + wc * 64 + j * 16 + lk * 4;
        float v[4];
        v[0] = rs * acc[i][j][0] - mrs * cj0[j].x + cj1[j].x;
        v[1] = rs * acc[i][j][1] - mrs * cj0[j].y + cj1[j].y;
        v[2] = rs * acc[i][j][2] - mrs * cj0[j].z + cj1[j].z;
        v[3] = rs * acc[i][j][3] - mrs * cj0[j].w + cj1[j].w;
        if (EPI == 5) {
          short4_t pk;
#pragma unroll
          for (int rr = 0; rr < 4; ++rr) pk[rr] = f2bf(v[rr]);
          *(short4_t*)((bf16*)C + (size_t)row * ldc + col) = pk;
        } else if (EPI == 6) {
          short4_t pk;
#pragma unroll
          for (int rr = 0; rr < 4; ++rr)
            pk[rr] = f2bf(v[rr] / (1.f + __expf(-1.702f * v[rr])));
          *(short4_t*)((bf16*)C + (size_t)row * ldc + col) = pk;
        } else {
          const size_t orow = (size_t)(row & 63) * SL + (row >> 6);
          float4 o4 = {v[0], v[1], v[2], v[3]};
          *(float4*)((float*)C + orow * ldc + col) = o4;
        }
      }
    } else {
      // EPI 8 / 9: residual update + row-stat emission
      float s1 = 0.f, s2 = 0.f;
#pragma unroll
      for (int j = 0; j < 4; ++j) {
        const int col = n0 + wc * 64 + j * 16 + lk * 4;
        const size_t off = (size_t)row * ldc + col;
        const float bv[4] = {cj0[j].x, cj0[j].y, cj0[j].z, cj0[j].w};
        short4_t xv = *(const short4_t*)((const bf16*)C + off);
        float4 h4;
        if (EPI == 9) h4 = *(const float4*)&hook[off];
        const float hk[4] = {h4.x, h4.y, h4.z, h4.w};
        short4_t pk;
#pragma unroll
        for (int rr = 0; rr < 4; ++rr) {
          float t = bf2f(xv[rr]) + acc[i][j][rr] + bv[rr];
          if (EPI == 9) t = wmg * hk[rr] + omg * t;
          s1 += t;
          s2 += t * t;
          pk[rr] = f2bf(t);
        }
        *(short4_t*)((bf16*)C + off) = pk;
      }
      s1 += __shfl_xor(s1, 16);
      s1 += __shfl_xor(s1, 32);
      s2 += __shfl_xor(s2, 16);
      s2 += __shfl_xor(s2, 32);
      if (lk == 0) {
        atomicAdd(&statsOut[row].x, s1);
        atomicAdd(&statsOut[row].y, s2);
      }
    }
  }
}

// ---------------- driver ----------------
extern "C" void kernel_launch(void* const* d_in, const int* in_sizes, int n_in,
                              void* d_out, int out_size, void* d_ws, size_t ws_size,
                              hipStream_t stream) {
  const float* hook = (const float*)d_in[0];
  const float* alpha = (const float*)d_in[1];
  const float* ipw = (const float*)d_in[2];
  const float* ipb = (const float*)d_in[3];
  const float* opw = (const float*)d_in[4];
  const float* opb = (const float*)d_in[5];
  const float* l1w = (const float*)d_in[6];
  const float* l1b = (const float*)d_in[7];
  const float* l2w = (const float*)d_in[8];
  const float* l2b = (const float*)d_in[9];
  const float* fcw = (const float*)d_in[10];
  const float* fcb = (const float*)d_in[11];
  const float* cpw = (const float*)d_in[12];
  const float* cpb = (const float*)d_in[13];
  const float* lpw = (const float*)d_in[14];
  const float* lpb = (const float*)d_in[15];
  const float* proj = (const float*)d_in[16];

  char* ws = (char*)d_ws;
  size_t off = 0;
  bf16* x = (bf16*)(ws + off); off += (size_t)MP * DM * 2;
  bf16* qkv = (bf16*)(ws + off);
  bf16* mbuf = (bf16*)qkv;  // reuse qkv region for MLP intermediate
  off += (size_t)MP * 1024 * 2;
  bf16* obuf = (bf16*)(ws + off); off += (size_t)MP * DRED * 2;
  bf16* wq = (bf16*)(ws + off); off += (size_t)KBLK * 768 * DM * 2;
  bf16* wo = (bf16*)(ws + off); off += (size_t)KBLK * DM * DRED * 2;
  bf16* wfc = (bf16*)(ws + off); off += (size_t)KBLK * DM * DM * 2;
  bf16* wcp = (bf16*)(ws + off); off += (size_t)KBLK * DM * DM * 2;
  bf16* wpj = (bf16*)(ws + off); off += (size_t)768 * DM * 2;
  float2* stats = (float2*)(ws + off); off += (size_t)13 * MR * sizeof(float2);
  float* sq_q = (float*)(ws + off); off += (size_t)KBLK * 768 * 4;
  float* bb_q = (float*)(ws + off); off += (size_t)KBLK * 768 * 4;
  float* sq_fc = (float*)(ws + off); off += (size_t)KBLK * DM * 4;
  float* bb_fc = (float*)(ws + off); off += (size_t)KBLK * DM * 4;
  float* sq_pj = (float*)(ws + off); off += (size_t)768 * 4;
  float* bb_pj = (float*)(ws + off); off += (size_t)768 * 4;

  cast_all_kernel<<<9600 + MR, 256, 0, stream>>>(
      ipw, opw, fcw, cpw, proj, l1w, l1b, l2w, l2b, lpw, lpb, ipb, fcb,
      hook, x,
      wq, wo, wfc, wcp, wpj, sq_q, bb_q, sq_fc, bb_fc, sq_pj, bb_pj, stats);

  const dim3 gq(129, 6);   // N=768 grids: 774 wgs
  const dim3 gm(129, 8);   // N=1024 grids: 1032 wgs

  for (int i = 0; i < KBLK; ++i) {
    const float2* stIn = (i == 0) ? stats + (size_t)12 * MR
                                  : stats + (size_t)(2 * i - 1) * MR;
    // qkv = LN1(x) @ ipw^T + ipb   (fused LN via folded weights)
    gemm_kernel<5, 1024, 6><<<gq, 256, 0, stream>>>(
        x, DM, wq + (size_t)i * 768 * DM, DM, nullptr, qkv, 768,
        nullptr, nullptr, 0, stIn, sq_q + i * 768, bb_q + i * 768, nullptr);
    attn_mfma_kernel<<<BA * NHEAD, 256, 0, stream>>>(qkv, obuf);
    // x += attn_out @ opw^T + opb ; emit LN2 stats
    gemm_kernel<8, 256, 8><<<gm, 256, 0, stream>>>(
        obuf, DRED, wo + (size_t)i * DM * DRED, DRED, opb + i * DM, x, DM,
        nullptr, nullptr, 0, nullptr, nullptr, nullptr,
        stats + (size_t)(2 * i) * MR);
    // mbuf = quickgelu(LN2(x) @ fcw^T + fcb)  (fused LN)
    gemm_kernel<6, 1024, 8><<<gm, 256, 0, stream>>>(
        x, DM, wfc + (size_t)i * DM * DM, DM, nullptr, mbuf, DM,
        nullptr, nullptr, 0, stats + (size_t)(2 * i) * MR,
        sq_fc + i * DM, bb_fc + i * DM, nullptr);
    // x = [gate_{i+1}] (x + mbuf @ cpw^T + cpb) ; emit LN1(i+1)/LNpost stats
    if (i + 1 < KBLK)
      gemm_kernel<9, 1024, 8><<<gm, 256, 0, stream>>>(
          mbuf, DM, wcp + (size_t)i * DM * DM, DM, cpb + i * DM, x, DM,
          hook + (size_t)(i + 1) * MR * DM, alpha, i + 1,
          nullptr, nullptr, nullptr, stats + (size_t)(2 * i + 1) * MR);
    else
      gemm_kernel<8, 1024, 8><<<gm, 256, 0, stream>>>(
          mbuf, DM, wcp + (size_t)i * DM * DM, DM, cpb + i * DM, x, DM,
          nullptr, nullptr, 0, nullptr, nullptr, nullptr,
          stats + (size_t)(2 * i + 1) * MR);
  }
  // final: out[b*SL+s] = LN_post(x) @ proj  (fused LN, transposed write, fp32)
  gemm_kernel<7, 1024, 6><<<gq, 256, 0, stream>>>(
      x, DM, wpj, DM, nullptr, (float*)d_out, 768,
      nullptr, nullptr, 0, stats + (size_t)11 * MR, sq_pj, bb_pj, nullptr);
}